// Round 3
// baseline (2525.212 us; speedup 1.0000x reference)
//
#include <hip/hip_runtime.h>
#include <cstdint>

#define N_USERS 100000
#define N_ITEMS 50000
#define N_NODES (N_USERS + N_ITEMS)
#define EMB 64
#define N_EDGES 4000000
#define LN_EPS 1e-5f

// ---------------------------------------------------------------------------
// Wave-batch encoder: y = LeakyReLU(LayerNorm(x @ W + b) * g + be, 0.2)
// lane = output dim (64 = wave width); each wave owns WR=16 rows.
// X loads are wave-uniform (scalar/broadcast, each row read once, contiguous);
// W rows loaded coalesced once per 16 rows; LN = 64-lane shfl_xor reduction.
// ---------------------------------------------------------------------------
template<int K, int WR>
__global__ __launch_bounds__(256) void encode_wave_kernel(
    const float* __restrict__ X, const float* __restrict__ W,
    const float* __restrict__ b, const float* __restrict__ g,
    const float* __restrict__ be, float* __restrict__ out, int R)
{
    int wave = __builtin_amdgcn_readfirstlane(blockIdx.x * 4 + (threadIdx.x >> 6));
    int lane = threadIdx.x & 63;
    int r0 = wave * WR;
    if (r0 >= R) return;

    const float* xrow[WR];
    #pragma unroll
    for (int r = 0; r < WR; ++r) {
        int rr = r0 + r; if (rr >= R) rr = R - 1;   // clamp (dup compute, store guarded)
        xrow[r] = X + (size_t)rr * K;
    }

    float bl = b[lane], gl = g[lane], bel = be[lane];
    float acc[WR];
    #pragma unroll
    for (int r = 0; r < WR; ++r) acc[r] = bl;

    const float* wcol = W + lane;
    for (int k0 = 0; k0 < K; k0 += 4) {
        float w0 = wcol[(k0 + 0) * EMB];
        float w1 = wcol[(k0 + 1) * EMB];
        float w2 = wcol[(k0 + 2) * EMB];
        float w3 = wcol[(k0 + 3) * EMB];
        #pragma unroll
        for (int r = 0; r < WR; ++r) {
            float4 xv = *reinterpret_cast<const float4*>(xrow[r] + k0);  // uniform addr
            acc[r] = fmaf(xv.x, w0, acc[r]);
            acc[r] = fmaf(xv.y, w1, acc[r]);
            acc[r] = fmaf(xv.z, w2, acc[r]);
            acc[r] = fmaf(xv.w, w3, acc[r]);
        }
    }

    #pragma unroll
    for (int r = 0; r < WR; ++r) {
        float s = acc[r];
        float q = acc[r] * acc[r];
        #pragma unroll
        for (int off = 32; off; off >>= 1) {
            s += __shfl_xor(s, off, 64);
            q += __shfl_xor(q, off, 64);
        }
        float mu = s * (1.f / EMB);
        float var = q * (1.f / EMB) - mu * mu;
        float rs = rsqrtf(var + LN_EPS);
        float t = (acc[r] - mu) * rs * gl + bel;
        t = t > 0.f ? t : 0.2f * t;
        if (r0 + r < R) out[(size_t)(r0 + r) * EMB + lane] = t;
    }
}

__global__ __launch_bounds__(256) void colsum_kernel(
    const float* __restrict__ X, int n, float* __restrict__ sum)
{
    __shared__ float s[256];
    int tid = threadIdx.x;
    float p = 0.f;
    int stride = gridDim.x * 256;
    for (int i = blockIdx.x * 256 + tid; i < n; i += stride) p += X[i];
    s[tid] = p;
    __syncthreads();
    if (tid < 64)
        unsafeAtomicAdd(&sum[tid], s[tid] + s[tid + 64] + s[tid + 128] + s[tid + 192]);
}

// hdr: [0:64) u_sum [64:128) um_sum [128:192) u_mean [192:256) m2_vec [256:320) pre1
__global__ void finalize_kernel(const float* __restrict__ aW1,
                                const float* __restrict__ ab1,
                                float* __restrict__ hdr)
{
    int d = threadIdx.x; // 64 threads
    float um = hdr[d] * (1.f / N_USERS);
    float m2 = hdr[64 + d] * (1.f / N_USERS);
    hdr[128 + d] = um;
    hdr[192 + d] = m2;
    float acc = ab1[d];
    for (int k = 0; k < EMB; ++k)
        acc = fmaf(hdr[k] * (1.f / N_USERS), aW1[k * EMB + d], acc);
    hdr[256 + d] = acc;
}

__global__ void copy_kernel(const float* __restrict__ a, float* __restrict__ o, int n4)
{
    int i = blockIdx.x * blockDim.x + threadIdx.x;
    int stride = gridDim.x * blockDim.x;
    const float4* A = reinterpret_cast<const float4*>(a);
    float4* O = reinterpret_cast<float4*>(o);
    for (; i < n4; i += stride) O[i] = A[i];
}

__global__ __launch_bounds__(256) void item_fuse_kernel(
    const float* __restrict__ item_emb, const float* __restrict__ m0,
    const float* __restrict__ m1, const float* __restrict__ hdr,
    const float* __restrict__ aW1, const float* __restrict__ aW2,
    const float* __restrict__ ab2, float* __restrict__ e0)
{
    int i = blockIdx.x * 256 + threadIdx.x;
    if (i >= N_ITEMS) return;
    float ie[EMB];
    const float4* ir = reinterpret_cast<const float4*>(item_emb + (size_t)i * EMB);
    #pragma unroll
    for (int q = 0; q < 16; ++q) {
        float4 v = ir[q];
        ie[q*4+0] = v.x; ie[q*4+1] = v.y; ie[q*4+2] = v.z; ie[q*4+3] = v.w;
    }
    float s0 = ab2[0], s1 = ab2[1], s2 = ab2[2];
    #pragma unroll
    for (int d0 = 0; d0 < EMB; d0 += 16) {
        float acc[16];
        #pragma unroll
        for (int j = 0; j < 16; ++j) acc[j] = hdr[256 + d0 + j];
        #pragma unroll
        for (int k = 0; k < EMB; ++k) {
            #pragma unroll
            for (int j = 0; j < 16; ++j)
                acc[j] = fmaf(ie[k], aW1[(64 + k) * EMB + d0 + j], acc[j]);
        }
        #pragma unroll
        for (int j = 0; j < 16; ++j) {
            float t = tanhf(acc[j]);
            int d = d0 + j;
            s0 = fmaf(t, aW2[d * 3 + 0], s0);
            s1 = fmaf(t, aW2[d * 3 + 1], s1);
            s2 = fmaf(t, aW2[d * 3 + 2], s2);
        }
    }
    float mx = fmaxf(s0, fmaxf(s1, s2));
    float ew0 = expf(s0 - mx), ew1 = expf(s1 - mx), ew2 = expf(s2 - mx);
    float inv = 1.f / (ew0 + ew1 + ew2);
    float w0 = ew0 * inv, w1 = ew1 * inv, w2 = ew2 * inv;

    const float4* r0 = reinterpret_cast<const float4*>(m0 + (size_t)i * EMB);
    const float4* r1 = reinterpret_cast<const float4*>(m1 + (size_t)i * EMB);
    float4* orow = reinterpret_cast<float4*>(e0 + (size_t)(N_USERS + i) * EMB);
    #pragma unroll
    for (int q = 0; q < 16; ++q) {
        float4 a = r0[q], bq = r1[q];
        float4 res;
        res.x = ie[q*4+0] + w0*a.x + w1*bq.x + w2*hdr[192 + q*4+0];
        res.y = ie[q*4+1] + w0*a.y + w1*bq.y + w2*hdr[192 + q*4+1];
        res.z = ie[q*4+2] + w0*a.z + w1*bq.z + w2*hdr[192 + q*4+2];
        res.w = ie[q*4+3] + w0*a.w + w1*bq.w + w2*hdr[192 + q*4+3];
        orow[q] = res;
    }
}

// ---------------------------------------------------------------------------
// On-device CSR build: histogram -> single-block scan -> scatter(packed int2)
// ---------------------------------------------------------------------------
__global__ __launch_bounds__(256) void hist_kernel(const int* __restrict__ rows,
                                                   int* __restrict__ cnt)
{
    int i = blockIdx.x * 256 + threadIdx.x;
    int stride = gridDim.x * 256;
    for (; i < N_EDGES; i += stride) atomicAdd(&cnt[rows[i]], 1);
}

__global__ __launch_bounds__(1024) void scan_kernel(const int* __restrict__ cnt,
                                                    int* __restrict__ offs)
{
    __shared__ int s[1024];
    const int CH = (N_NODES + 1023) / 1024; // 147
    int t = threadIdx.x;
    int base = t * CH;
    int sum = 0;
    for (int i = 0; i < CH; ++i) {
        int idx = base + i;
        if (idx < N_NODES) sum += cnt[idx];
    }
    s[t] = sum;
    __syncthreads();
    for (int off = 1; off < 1024; off <<= 1) {
        int v = (t >= off) ? s[t - off] : 0;
        __syncthreads();
        s[t] += v;
        __syncthreads();
    }
    int run = (t == 0) ? 0 : s[t - 1]; // exclusive base for this chunk
    for (int i = 0; i < CH; ++i) {
        int idx = base + i;
        if (idx < N_NODES) { offs[idx] = run; run += cnt[idx]; }
    }
}

// scatter bumps offs[r]: afterwards offs[r] == end-of-row-r (inclusive prefix)
__global__ __launch_bounds__(256) void scatter_kernel(
    const float* __restrict__ vals, const int* __restrict__ rows,
    const int* __restrict__ cols, int* __restrict__ offs,
    int2* __restrict__ edges)
{
    int i = blockIdx.x * 256 + threadIdx.x;
    int stride = gridDim.x * 256;
    for (; i < N_EDGES; i += stride) {
        int r = rows[i];
        int pos = atomicAdd(&offs[r], 1);
        edges[pos] = make_int2(cols[i], __float_as_int(vals[i]));
    }
}

// ---------------------------------------------------------------------------
// CSR SpMM: one 64-lane wave per row, lane = dim. Wave-uniform row index
// (readfirstlane) -> edge reads scalarize; coalesced 256B gathers, no atomics.
// FINAL variant fuses out = (e0 + e1 + A*e1) / 3.
// ---------------------------------------------------------------------------
template<int FINAL>
__global__ __launch_bounds__(256) void spmm_csr_kernel(
    const int* __restrict__ offs, const int2* __restrict__ edges,
    const float* __restrict__ src, const float* __restrict__ e0,
    const float* __restrict__ e1, float* __restrict__ dst)
{
    int r = __builtin_amdgcn_readfirstlane(blockIdx.x * 4 + (threadIdx.x >> 6));
    if (r >= N_NODES) return;
    int d = threadIdx.x & 63;
    int start = (r == 0) ? 0 : offs[r - 1];
    int end = offs[r];
    float acc0 = 0.f, acc1 = 0.f;
    int i = start;
    for (; i + 2 <= end; i += 2) {
        int2 p0 = edges[i], p1 = edges[i + 1];
        float v0 = __int_as_float(p0.y), v1 = __int_as_float(p1.y);
        acc0 = fmaf(v0, src[(size_t)p0.x * EMB + d], acc0);
        acc1 = fmaf(v1, src[(size_t)p1.x * EMB + d], acc1);
    }
    if (i < end) {
        int2 p = edges[i];
        acc0 = fmaf(__int_as_float(p.y), src[(size_t)p.x * EMB + d], acc0);
    }
    float s = acc0 + acc1;
    size_t idx = (size_t)r * EMB + d;
    if (FINAL)
        dst[idx] = (e0[idx] + e1[idx] + s) * (1.f / 3.f);
    else
        dst[idx] = s;
}

extern "C" void kernel_launch(void* const* d_in, const int* in_sizes, int n_in,
                              void* d_out, int out_size, void* d_ws, size_t ws_size,
                              hipStream_t stream)
{
    const float* user_emb = (const float*)d_in[0];
    const float* item_emb = (const float*)d_in[1];
    const float* mf0 = (const float*)d_in[2];
    const float* mf1 = (const float*)d_in[3];
    const float* mf2 = (const float*)d_in[4];
    const float* W0  = (const float*)d_in[5];
    const float* b0  = (const float*)d_in[6];
    const float* g0  = (const float*)d_in[7];
    const float* be0 = (const float*)d_in[8];
    const float* W1  = (const float*)d_in[9];
    const float* b1  = (const float*)d_in[10];
    const float* g1  = (const float*)d_in[11];
    const float* be1 = (const float*)d_in[12];
    const float* W2  = (const float*)d_in[13];
    const float* b2  = (const float*)d_in[14];
    const float* g2  = (const float*)d_in[15];
    const float* be2 = (const float*)d_in[16];
    const float* aW1 = (const float*)d_in[17];
    const float* ab1 = (const float*)d_in[18];
    const float* aW2 = (const float*)d_in[19];
    const float* ab2 = (const float*)d_in[20];
    const float* avals = (const float*)d_in[21];
    const int* arows = (const int*)d_in[22];
    const int* acols = (const int*)d_in[23];
    float* out = (float*)d_out;

    float* ws  = (float*)d_ws;
    float* hdr = ws;                                   // 512 floats
    float* m0b = ws + 512;                             // 50000*64
    float* m1b = m0b + (size_t)N_ITEMS * EMB;          // 50000*64
    float* e0  = m1b + (size_t)N_ITEMS * EMB;          // 150000*64
    float* e1  = e0 + (size_t)N_NODES * EMB;           // 150000*64
    int*   cnt = (int*)(e1 + (size_t)N_NODES * EMB);   // 150000 ints
    int*   offs = cnt + N_NODES;                       // 150000 ints
    int2*  edges = (int2*)(offs + N_NODES);            // 4M int2 (32 MB)
    float* umb = e1;  // um aliases e1; consumed before spmm1 writes e1

    hipMemsetAsync(hdr, 0, 128 * sizeof(float), stream);
    hipMemsetAsync(cnt, 0, N_NODES * sizeof(int), stream);

    // CSR build (independent of embedding pipeline)
    hist_kernel<<<2048, 256, 0, stream>>>(arows, cnt);
    scan_kernel<<<1, 1024, 0, stream>>>(cnt, offs);
    scatter_kernel<<<2048, 256, 0, stream>>>(avals, arows, acols, offs, edges);

    // embedding pipeline (wave-batch encoders: 64 rows per 256-thread block)
    colsum_kernel<<<256, 256, 0, stream>>>(user_emb, N_USERS * EMB, hdr);   // u_sum
    encode_wave_kernel<128, 16><<<(N_USERS + 63) / 64, 256, 0, stream>>>(mf2, W2, b2, g2, be2, umb, N_USERS);
    colsum_kernel<<<256, 256, 0, stream>>>(umb, N_USERS * EMB, hdr + 64);   // um_sum
    finalize_kernel<<<1, 64, 0, stream>>>(aW1, ab1, hdr);
    encode_wave_kernel<768, 16><<<(N_ITEMS + 63) / 64, 256, 0, stream>>>(mf0, W0, b0, g0, be0, m0b, N_ITEMS);
    encode_wave_kernel<384, 16><<<(N_ITEMS + 63) / 64, 256, 0, stream>>>(mf1, W1, b1, g1, be1, m1b, N_ITEMS);
    copy_kernel<<<1024, 256, 0, stream>>>(user_emb, e0, N_USERS * EMB / 4);
    item_fuse_kernel<<<(N_ITEMS + 255) / 256, 256, 0, stream>>>(item_emb, m0b, m1b, hdr, aW1, aW2, ab2, e0);

    // two propagation layers, no atomics
    spmm_csr_kernel<0><<<(N_NODES + 3) / 4, 256, 0, stream>>>(offs, edges, e0, e0, e1, e1);
    spmm_csr_kernel<1><<<(N_NODES + 3) / 4, 256, 0, stream>>>(offs, edges, e1, e0, e1, out);
}

// Round 4
// 1517.155 us; speedup vs baseline: 1.6644x; 1.6644x over previous
//
#include <hip/hip_runtime.h>
#include <cstdint>

#define N_USERS 100000
#define N_ITEMS 50000
#define N_NODES (N_USERS + N_ITEMS)
#define EMB 64
#define N_EDGES 4000000
#define LN_EPS 1e-5f

// ---------------------------------------------------------------------------
// Tiled-GEMM encoder: y = LeakyReLU(LayerNorm(x @ W + b) * g + be, 0.2)
// Block = 256 threads = 64x64 output tile; K staged in 32-chunks.
// sXT stored transposed [k][row] (+4 pad) -> inner loop is 2x ds_read_b128
// + 16 FMA per k. LN: 16 lanes sharing a row reduce via shfl_xor(1,2,4,8).
// WRITE_OUT=0: skip output entirely, accumulate column sums into colsum[64]
// (used for enc2, whose output is only ever column-averaged).
// ---------------------------------------------------------------------------
template<int K, int WRITE_OUT>
__global__ __launch_bounds__(256) void encode_gemm_kernel(
    const float* __restrict__ X, const float* __restrict__ W,
    const float* __restrict__ b, const float* __restrict__ g,
    const float* __restrict__ be, float* __restrict__ out,
    float* __restrict__ colsum, int R)
{
    __shared__ float sXT[32][68];   // [k][row], pad 4: 16B-aligned rows (68*4=272)
    __shared__ float sW[32][64];    // [k][col]
    __shared__ float scs[64];

    int tid = threadIdx.x;
    int tx = tid & 15;              // col group: cols tx*4 .. tx*4+3
    int ty = tid >> 4;              // row group: rows ty*4 .. ty*4+3
    int rbase = blockIdx.x * 64;

    // staging indices
    int xr = tid >> 2;              // 0..63 tile row
    int xc = (tid & 3) * 8;         // 0..24 chunk col (8 floats)
    int wr = tid >> 3;              // 0..31 chunk row
    int wc = (tid & 7) * 8;         // 0..56 col (8 floats)

    int gxrow = rbase + xr; if (gxrow >= R) gxrow = R - 1;   // clamp; stores guarded
    const float* xsrc = X + (size_t)gxrow * K + xc;

    float4 bv = *reinterpret_cast<const float4*>(&b[tx * 4]);
    float4 gv = *reinterpret_cast<const float4*>(&g[tx * 4]);
    float4 bev = *reinterpret_cast<const float4*>(&be[tx * 4]);

    float acc[4][4];
    #pragma unroll
    for (int i = 0; i < 4; ++i) {
        acc[i][0] = bv.x; acc[i][1] = bv.y; acc[i][2] = bv.z; acc[i][3] = bv.w;
    }

    for (int kc = 0; kc < K; kc += 32) {
        float4 a0 = *reinterpret_cast<const float4*>(xsrc + kc);
        float4 a1 = *reinterpret_cast<const float4*>(xsrc + kc + 4);
        float4 w0 = *reinterpret_cast<const float4*>(&W[(size_t)(kc + wr) * EMB + wc]);
        float4 w1 = *reinterpret_cast<const float4*>(&W[(size_t)(kc + wr) * EMB + wc + 4]);
        __syncthreads();   // protect previous chunk's consumers
        sXT[xc + 0][xr] = a0.x; sXT[xc + 1][xr] = a0.y;
        sXT[xc + 2][xr] = a0.z; sXT[xc + 3][xr] = a0.w;
        sXT[xc + 4][xr] = a1.x; sXT[xc + 5][xr] = a1.y;
        sXT[xc + 6][xr] = a1.z; sXT[xc + 7][xr] = a1.w;
        *reinterpret_cast<float4*>(&sW[wr][wc]) = w0;
        *reinterpret_cast<float4*>(&sW[wr][wc + 4]) = w1;
        __syncthreads();
        #pragma unroll
        for (int k = 0; k < 32; ++k) {
            float4 xv = *reinterpret_cast<const float4*>(&sXT[k][ty * 4]);
            float4 wv = *reinterpret_cast<const float4*>(&sW[k][tx * 4]);
            float xs[4] = {xv.x, xv.y, xv.z, xv.w};
            float wsv[4] = {wv.x, wv.y, wv.z, wv.w};
            #pragma unroll
            for (int i = 0; i < 4; ++i)
                #pragma unroll
                for (int j = 0; j < 4; ++j)
                    acc[i][j] = fmaf(xs[i], wsv[j], acc[i][j]);
        }
    }

    // per-row LayerNorm + LeakyReLU (rows = ty*4+i, 16 lanes per row share tx)
    float gls[4] = {gv.x, gv.y, gv.z, gv.w};
    float bels[4] = {bev.x, bev.y, bev.z, bev.w};
    float csum[4] = {0.f, 0.f, 0.f, 0.f};
    #pragma unroll
    for (int i = 0; i < 4; ++i) {
        float s = acc[i][0] + acc[i][1] + acc[i][2] + acc[i][3];
        float q = acc[i][0]*acc[i][0] + acc[i][1]*acc[i][1]
                + acc[i][2]*acc[i][2] + acc[i][3]*acc[i][3];
        #pragma unroll
        for (int off = 1; off < 16; off <<= 1) {
            s += __shfl_xor(s, off, 64);
            q += __shfl_xor(q, off, 64);
        }
        float mu = s * (1.f / EMB);
        float var = q * (1.f / EMB) - mu * mu;
        float rs = rsqrtf(var + LN_EPS);
        int row = rbase + ty * 4 + i;
        bool valid = row < R;
        float t[4];
        #pragma unroll
        for (int j = 0; j < 4; ++j) {
            float v = (acc[i][j] - mu) * rs * gls[j] + bels[j];
            t[j] = v > 0.f ? v : 0.2f * v;
        }
        if (WRITE_OUT) {
            if (valid)
                *reinterpret_cast<float4*>(&out[(size_t)row * EMB + tx * 4]) =
                    make_float4(t[0], t[1], t[2], t[3]);
        } else {
            #pragma unroll
            for (int j = 0; j < 4; ++j) csum[j] += valid ? t[j] : 0.f;
        }
    }

    if (!WRITE_OUT) {
        // reduce ty-within-wave (lanes l, l^16, l^32), then LDS, then global
        #pragma unroll
        for (int j = 0; j < 4; ++j) {
            csum[j] += __shfl_xor(csum[j], 16, 64);
            csum[j] += __shfl_xor(csum[j], 32, 64);
        }
        if (tid < 64) scs[tid] = 0.f;
        __syncthreads();
        if ((tid & 63) < 16) {
            #pragma unroll
            for (int j = 0; j < 4; ++j) atomicAdd(&scs[tx * 4 + j], csum[j]);
        }
        __syncthreads();
        if (tid < 64) unsafeAtomicAdd(&colsum[tid], scs[tid]);
    }
}

__global__ __launch_bounds__(256) void colsum_kernel(
    const float* __restrict__ X, int n, float* __restrict__ sum)
{
    __shared__ float s[256];
    int tid = threadIdx.x;
    float p = 0.f;
    int stride = gridDim.x * 256;
    for (int i = blockIdx.x * 256 + tid; i < n; i += stride) p += X[i];
    s[tid] = p;
    __syncthreads();
    if (tid < 64)
        unsafeAtomicAdd(&sum[tid], s[tid] + s[tid + 64] + s[tid + 128] + s[tid + 192]);
}

// hdr: [0:64) u_sum [64:128) um_sum [128:192) u_mean [192:256) m2_vec [256:320) pre1
__global__ void finalize_kernel(const float* __restrict__ aW1,
                                const float* __restrict__ ab1,
                                float* __restrict__ hdr)
{
    int d = threadIdx.x; // 64 threads
    float um = hdr[d] * (1.f / N_USERS);
    float m2 = hdr[64 + d] * (1.f / N_USERS);
    hdr[128 + d] = um;
    hdr[192 + d] = m2;
    float acc = ab1[d];
    for (int k = 0; k < EMB; ++k)
        acc = fmaf(hdr[k] * (1.f / N_USERS), aW1[k * EMB + d], acc);
    hdr[256 + d] = acc;
}

__global__ void copy_kernel(const float* __restrict__ a, float* __restrict__ o, int n4)
{
    int i = blockIdx.x * blockDim.x + threadIdx.x;
    int stride = gridDim.x * blockDim.x;
    const float4* A = reinterpret_cast<const float4*>(a);
    float4* O = reinterpret_cast<float4*>(o);
    for (; i < n4; i += stride) O[i] = A[i];
}

__global__ __launch_bounds__(256) void item_fuse_kernel(
    const float* __restrict__ item_emb, const float* __restrict__ m0,
    const float* __restrict__ m1, const float* __restrict__ hdr,
    const float* __restrict__ aW1, const float* __restrict__ aW2,
    const float* __restrict__ ab2, float* __restrict__ e0)
{
    int i = blockIdx.x * 256 + threadIdx.x;
    if (i >= N_ITEMS) return;
    float ie[EMB];
    const float4* ir = reinterpret_cast<const float4*>(item_emb + (size_t)i * EMB);
    #pragma unroll
    for (int q = 0; q < 16; ++q) {
        float4 v = ir[q];
        ie[q*4+0] = v.x; ie[q*4+1] = v.y; ie[q*4+2] = v.z; ie[q*4+3] = v.w;
    }
    float s0 = ab2[0], s1 = ab2[1], s2 = ab2[2];
    #pragma unroll
    for (int d0 = 0; d0 < EMB; d0 += 16) {
        float acc[16];
        #pragma unroll
        for (int j = 0; j < 16; ++j) acc[j] = hdr[256 + d0 + j];
        #pragma unroll
        for (int k = 0; k < EMB; ++k) {
            #pragma unroll
            for (int j = 0; j < 16; ++j)
                acc[j] = fmaf(ie[k], aW1[(64 + k) * EMB + d0 + j], acc[j]);
        }
        #pragma unroll
        for (int j = 0; j < 16; ++j) {
            float t = tanhf(acc[j]);
            int d = d0 + j;
            s0 = fmaf(t, aW2[d * 3 + 0], s0);
            s1 = fmaf(t, aW2[d * 3 + 1], s1);
            s2 = fmaf(t, aW2[d * 3 + 2], s2);
        }
    }
    float mx = fmaxf(s0, fmaxf(s1, s2));
    float ew0 = expf(s0 - mx), ew1 = expf(s1 - mx), ew2 = expf(s2 - mx);
    float inv = 1.f / (ew0 + ew1 + ew2);
    float w0 = ew0 * inv, w1 = ew1 * inv, w2 = ew2 * inv;

    const float4* r0 = reinterpret_cast<const float4*>(m0 + (size_t)i * EMB);
    const float4* r1 = reinterpret_cast<const float4*>(m1 + (size_t)i * EMB);
    float4* orow = reinterpret_cast<float4*>(e0 + (size_t)(N_USERS + i) * EMB);
    #pragma unroll
    for (int q = 0; q < 16; ++q) {
        float4 a = r0[q], bq = r1[q];
        float4 res;
        res.x = ie[q*4+0] + w0*a.x + w1*bq.x + w2*hdr[192 + q*4+0];
        res.y = ie[q*4+1] + w0*a.y + w1*bq.y + w2*hdr[192 + q*4+1];
        res.z = ie[q*4+2] + w0*a.z + w1*bq.z + w2*hdr[192 + q*4+2];
        res.w = ie[q*4+3] + w0*a.w + w1*bq.w + w2*hdr[192 + q*4+3];
        orow[q] = res;
    }
}

// ---------------------------------------------------------------------------
// On-device CSR build: histogram -> single-block scan -> scatter(packed int2)
// ---------------------------------------------------------------------------
__global__ __launch_bounds__(256) void hist_kernel(const int* __restrict__ rows,
                                                   int* __restrict__ cnt)
{
    int i = blockIdx.x * 256 + threadIdx.x;
    int stride = gridDim.x * 256;
    for (; i < N_EDGES; i += stride) atomicAdd(&cnt[rows[i]], 1);
}

__global__ __launch_bounds__(1024) void scan_kernel(const int* __restrict__ cnt,
                                                    int* __restrict__ offs)
{
    __shared__ int s[1024];
    const int CH = (N_NODES + 1023) / 1024; // 147
    int t = threadIdx.x;
    int base = t * CH;
    int sum = 0;
    for (int i = 0; i < CH; ++i) {
        int idx = base + i;
        if (idx < N_NODES) sum += cnt[idx];
    }
    s[t] = sum;
    __syncthreads();
    for (int off = 1; off < 1024; off <<= 1) {
        int v = (t >= off) ? s[t - off] : 0;
        __syncthreads();
        s[t] += v;
        __syncthreads();
    }
    int run = (t == 0) ? 0 : s[t - 1]; // exclusive base for this chunk
    for (int i = 0; i < CH; ++i) {
        int idx = base + i;
        if (idx < N_NODES) { offs[idx] = run; run += cnt[idx]; }
    }
}

// scatter bumps offs[r]: afterwards offs[r] == end-of-row-r (inclusive prefix)
__global__ __launch_bounds__(256) void scatter_kernel(
    const float* __restrict__ vals, const int* __restrict__ rows,
    const int* __restrict__ cols, int* __restrict__ offs,
    int2* __restrict__ edges)
{
    int i = blockIdx.x * 256 + threadIdx.x;
    int stride = gridDim.x * 256;
    for (; i < N_EDGES; i += stride) {
        int r = rows[i];
        int pos = atomicAdd(&offs[r], 1);
        edges[pos] = make_int2(cols[i], __float_as_int(vals[i]));
    }
}

// ---------------------------------------------------------------------------
// CSR SpMM: one 64-lane wave per row, lane = dim. Coalesced 256B gathers,
// no atomics. FINAL fuses out = (e0 + e1 + A*e1) / 3.
// ---------------------------------------------------------------------------
template<int FINAL>
__global__ __launch_bounds__(256) void spmm_csr_kernel(
    const int* __restrict__ offs, const int2* __restrict__ edges,
    const float* __restrict__ src, const float* __restrict__ e0,
    const float* __restrict__ e1, float* __restrict__ dst)
{
    int r = __builtin_amdgcn_readfirstlane(blockIdx.x * 4 + (threadIdx.x >> 6));
    if (r >= N_NODES) return;
    int d = threadIdx.x & 63;
    int start = (r == 0) ? 0 : offs[r - 1];
    int end = offs[r];
    float acc0 = 0.f, acc1 = 0.f;
    int i = start;
    for (; i + 2 <= end; i += 2) {
        int2 p0 = edges[i], p1 = edges[i + 1];
        float v0 = __int_as_float(p0.y), v1 = __int_as_float(p1.y);
        acc0 = fmaf(v0, src[(size_t)p0.x * EMB + d], acc0);
        acc1 = fmaf(v1, src[(size_t)p1.x * EMB + d], acc1);
    }
    if (i < end) {
        int2 p = edges[i];
        acc0 = fmaf(__int_as_float(p.y), src[(size_t)p.x * EMB + d], acc0);
    }
    float s = acc0 + acc1;
    size_t idx = (size_t)r * EMB + d;
    if (FINAL)
        dst[idx] = (e0[idx] + e1[idx] + s) * (1.f / 3.f);
    else
        dst[idx] = s;
}

extern "C" void kernel_launch(void* const* d_in, const int* in_sizes, int n_in,
                              void* d_out, int out_size, void* d_ws, size_t ws_size,
                              hipStream_t stream)
{
    const float* user_emb = (const float*)d_in[0];
    const float* item_emb = (const float*)d_in[1];
    const float* mf0 = (const float*)d_in[2];
    const float* mf1 = (const float*)d_in[3];
    const float* mf2 = (const float*)d_in[4];
    const float* W0  = (const float*)d_in[5];
    const float* b0  = (const float*)d_in[6];
    const float* g0  = (const float*)d_in[7];
    const float* be0 = (const float*)d_in[8];
    const float* W1  = (const float*)d_in[9];
    const float* b1  = (const float*)d_in[10];
    const float* g1  = (const float*)d_in[11];
    const float* be1 = (const float*)d_in[12];
    const float* W2  = (const float*)d_in[13];
    const float* b2  = (const float*)d_in[14];
    const float* g2  = (const float*)d_in[15];
    const float* be2 = (const float*)d_in[16];
    const float* aW1 = (const float*)d_in[17];
    const float* ab1 = (const float*)d_in[18];
    const float* aW2 = (const float*)d_in[19];
    const float* ab2 = (const float*)d_in[20];
    const float* avals = (const float*)d_in[21];
    const int* arows = (const int*)d_in[22];
    const int* acols = (const int*)d_in[23];
    float* out = (float*)d_out;

    float* ws  = (float*)d_ws;
    float* hdr = ws;                                   // 512 floats
    float* m0b = ws + 512;                             // 50000*64
    float* m1b = m0b + (size_t)N_ITEMS * EMB;          // 50000*64
    float* e0  = m1b + (size_t)N_ITEMS * EMB;          // 150000*64
    float* e1  = e0 + (size_t)N_NODES * EMB;           // 150000*64
    int*   cnt = (int*)(e1 + (size_t)N_NODES * EMB);   // 150000 ints
    int*   offs = cnt + N_NODES;                       // 150000 ints
    int2*  edges = (int2*)(offs + N_NODES);            // 4M int2 (32 MB)

    hipMemsetAsync(hdr, 0, 128 * sizeof(float), stream);
    hipMemsetAsync(cnt, 0, N_NODES * sizeof(int), stream);

    // CSR build (independent of embedding pipeline)
    hist_kernel<<<2048, 256, 0, stream>>>(arows, cnt);
    scan_kernel<<<1, 1024, 0, stream>>>(cnt, offs);
    scatter_kernel<<<2048, 256, 0, stream>>>(avals, arows, acols, offs, edges);

    // embedding pipeline (tiled-GEMM encoders, 64x64 tile per block)
    colsum_kernel<<<256, 256, 0, stream>>>(user_emb, N_USERS * EMB, hdr);   // u_sum
    encode_gemm_kernel<128, 0><<<(N_USERS + 63) / 64, 256, 0, stream>>>(
        mf2, W2, b2, g2, be2, nullptr, hdr + 64, N_USERS);                  // um_sum fused
    finalize_kernel<<<1, 64, 0, stream>>>(aW1, ab1, hdr);
    encode_gemm_kernel<768, 1><<<(N_ITEMS + 63) / 64, 256, 0, stream>>>(
        mf0, W0, b0, g0, be0, m0b, nullptr, N_ITEMS);
    encode_gemm_kernel<384, 1><<<(N_ITEMS + 63) / 64, 256, 0, stream>>>(
        mf1, W1, b1, g1, be1, m1b, nullptr, N_ITEMS);
    copy_kernel<<<1024, 256, 0, stream>>>(user_emb, e0, N_USERS * EMB / 4);
    item_fuse_kernel<<<(N_ITEMS + 255) / 256, 256, 0, stream>>>(item_emb, m0b, m1b, hdr, aW1, aW2, ab2, e0);

    // two propagation layers, no atomics
    spmm_csr_kernel<0><<<(N_NODES + 3) / 4, 256, 0, stream>>>(offs, edges, e0, e0, e1, e1);
    spmm_csr_kernel<1><<<(N_NODES + 3) / 4, 256, 0, stream>>>(offs, edges, e1, e0, e1, out);
}

// Round 5
// 1073.950 us; speedup vs baseline: 2.3513x; 1.4127x over previous
//
#include <hip/hip_runtime.h>
#include <cstdint>

#define N_USERS 100000
#define N_ITEMS 50000
#define N_NODES (N_USERS + N_ITEMS)
#define EMB 64
#define N_EDGES 4000000
#define LN_EPS 1e-5f

#define NBKT 586          // ceil(N_NODES/256): buckets of 256 rows
#define C_BLOCKS 1024
#define EPB 3907          // ceil(N_EDGES/C_BLOCKS)

// ---------------------------------------------------------------------------
// Tiled-GEMM encoder: y = LeakyReLU(LayerNorm(x @ W + b) * g + be, 0.2)
// Block = 256 threads = 64x64 output tile; K staged in 32-chunks.
// WRITE_OUT=0: skip output, accumulate column sums into colsum[64] (enc2).
// ---------------------------------------------------------------------------
template<int K, int WRITE_OUT>
__global__ __launch_bounds__(256) void encode_gemm_kernel(
    const float* __restrict__ X, const float* __restrict__ W,
    const float* __restrict__ b, const float* __restrict__ g,
    const float* __restrict__ be, float* __restrict__ out,
    float* __restrict__ colsum, int R)
{
    __shared__ float sXT[32][68];
    __shared__ float sW[32][64];
    __shared__ float scs[64];

    int tid = threadIdx.x;
    int tx = tid & 15;
    int ty = tid >> 4;
    int rbase = blockIdx.x * 64;

    int xr = tid >> 2;
    int xc = (tid & 3) * 8;
    int wr = tid >> 3;
    int wc = (tid & 7) * 8;

    int gxrow = rbase + xr; if (gxrow >= R) gxrow = R - 1;
    const float* xsrc = X + (size_t)gxrow * K + xc;

    float4 bv = *reinterpret_cast<const float4*>(&b[tx * 4]);
    float4 gv = *reinterpret_cast<const float4*>(&g[tx * 4]);
    float4 bev = *reinterpret_cast<const float4*>(&be[tx * 4]);

    float acc[4][4];
    #pragma unroll
    for (int i = 0; i < 4; ++i) {
        acc[i][0] = bv.x; acc[i][1] = bv.y; acc[i][2] = bv.z; acc[i][3] = bv.w;
    }

    for (int kc = 0; kc < K; kc += 32) {
        float4 a0 = *reinterpret_cast<const float4*>(xsrc + kc);
        float4 a1 = *reinterpret_cast<const float4*>(xsrc + kc + 4);
        float4 w0 = *reinterpret_cast<const float4*>(&W[(size_t)(kc + wr) * EMB + wc]);
        float4 w1 = *reinterpret_cast<const float4*>(&W[(size_t)(kc + wr) * EMB + wc + 4]);
        __syncthreads();
        sXT[xc + 0][xr] = a0.x; sXT[xc + 1][xr] = a0.y;
        sXT[xc + 2][xr] = a0.z; sXT[xc + 3][xr] = a0.w;
        sXT[xc + 4][xr] = a1.x; sXT[xc + 5][xr] = a1.y;
        sXT[xc + 6][xr] = a1.z; sXT[xc + 7][xr] = a1.w;
        *reinterpret_cast<float4*>(&sW[wr][wc]) = w0;
        *reinterpret_cast<float4*>(&sW[wr][wc + 4]) = w1;
        __syncthreads();
        #pragma unroll
        for (int k = 0; k < 32; ++k) {
            float4 xv = *reinterpret_cast<const float4*>(&sXT[k][ty * 4]);
            float4 wv = *reinterpret_cast<const float4*>(&sW[k][tx * 4]);
            float xs[4] = {xv.x, xv.y, xv.z, xv.w};
            float wsv[4] = {wv.x, wv.y, wv.z, wv.w};
            #pragma unroll
            for (int i = 0; i < 4; ++i)
                #pragma unroll
                for (int j = 0; j < 4; ++j)
                    acc[i][j] = fmaf(xs[i], wsv[j], acc[i][j]);
        }
    }

    float gls[4] = {gv.x, gv.y, gv.z, gv.w};
    float bels[4] = {bev.x, bev.y, bev.z, bev.w};
    float csum[4] = {0.f, 0.f, 0.f, 0.f};
    #pragma unroll
    for (int i = 0; i < 4; ++i) {
        float s = acc[i][0] + acc[i][1] + acc[i][2] + acc[i][3];
        float q = acc[i][0]*acc[i][0] + acc[i][1]*acc[i][1]
                + acc[i][2]*acc[i][2] + acc[i][3]*acc[i][3];
        #pragma unroll
        for (int off = 1; off < 16; off <<= 1) {
            s += __shfl_xor(s, off, 64);
            q += __shfl_xor(q, off, 64);
        }
        float mu = s * (1.f / EMB);
        float var = q * (1.f / EMB) - mu * mu;
        float rs = rsqrtf(var + LN_EPS);
        int row = rbase + ty * 4 + i;
        bool valid = row < R;
        float t[4];
        #pragma unroll
        for (int j = 0; j < 4; ++j) {
            float v = (acc[i][j] - mu) * rs * gls[j] + bels[j];
            t[j] = v > 0.f ? v : 0.2f * v;
        }
        if (WRITE_OUT) {
            if (valid)
                *reinterpret_cast<float4*>(&out[(size_t)row * EMB + tx * 4]) =
                    make_float4(t[0], t[1], t[2], t[3]);
        } else {
            #pragma unroll
            for (int j = 0; j < 4; ++j) csum[j] += valid ? t[j] : 0.f;
        }
    }

    if (!WRITE_OUT) {
        #pragma unroll
        for (int j = 0; j < 4; ++j) {
            csum[j] += __shfl_xor(csum[j], 16, 64);
            csum[j] += __shfl_xor(csum[j], 32, 64);
        }
        if (tid < 64) scs[tid] = 0.f;
        __syncthreads();
        if ((tid & 63) < 16) {
            #pragma unroll
            for (int j = 0; j < 4; ++j) atomicAdd(&scs[tx * 4 + j], csum[j]);
        }
        __syncthreads();
        if (tid < 64) unsafeAtomicAdd(&colsum[tid], scs[tid]);
    }
}

__global__ __launch_bounds__(256) void colsum_kernel(
    const float* __restrict__ X, int n, float* __restrict__ sum)
{
    __shared__ float s[256];
    int tid = threadIdx.x;
    float p = 0.f;
    int stride = gridDim.x * 256;
    for (int i = blockIdx.x * 256 + tid; i < n; i += stride) p += X[i];
    s[tid] = p;
    __syncthreads();
    if (tid < 64)
        unsafeAtomicAdd(&sum[tid], s[tid] + s[tid + 64] + s[tid + 128] + s[tid + 192]);
}

// hdr: [0:64) u_sum [64:128) um_sum [128:192) u_mean [192:256) m2_vec [256:320) pre1
__global__ void finalize_kernel(const float* __restrict__ aW1,
                                const float* __restrict__ ab1,
                                float* __restrict__ hdr)
{
    int d = threadIdx.x; // 64 threads
    float um = hdr[d] * (1.f / N_USERS);
    float m2 = hdr[64 + d] * (1.f / N_USERS);
    hdr[128 + d] = um;
    hdr[192 + d] = m2;
    float acc = ab1[d];
    for (int k = 0; k < EMB; ++k)
        acc = fmaf(hdr[k] * (1.f / N_USERS), aW1[k * EMB + d], acc);
    hdr[256 + d] = acc;
}

__global__ void copy_kernel(const float* __restrict__ a, float* __restrict__ o, int n4)
{
    int i = blockIdx.x * blockDim.x + threadIdx.x;
    int stride = gridDim.x * blockDim.x;
    const float4* A = reinterpret_cast<const float4*>(a);
    float4* O = reinterpret_cast<float4*>(o);
    for (; i < n4; i += stride) O[i] = A[i];
}

__global__ __launch_bounds__(256) void item_fuse_kernel(
    const float* __restrict__ item_emb, const float* __restrict__ m0,
    const float* __restrict__ m1, const float* __restrict__ hdr,
    const float* __restrict__ aW1, const float* __restrict__ aW2,
    const float* __restrict__ ab2, float* __restrict__ e0)
{
    int i = blockIdx.x * 256 + threadIdx.x;
    if (i >= N_ITEMS) return;
    float ie[EMB];
    const float4* ir = reinterpret_cast<const float4*>(item_emb + (size_t)i * EMB);
    #pragma unroll
    for (int q = 0; q < 16; ++q) {
        float4 v = ir[q];
        ie[q*4+0] = v.x; ie[q*4+1] = v.y; ie[q*4+2] = v.z; ie[q*4+3] = v.w;
    }
    float s0 = ab2[0], s1 = ab2[1], s2 = ab2[2];
    #pragma unroll
    for (int d0 = 0; d0 < EMB; d0 += 16) {
        float acc[16];
        #pragma unroll
        for (int j = 0; j < 16; ++j) acc[j] = hdr[256 + d0 + j];
        #pragma unroll
        for (int k = 0; k < EMB; ++k) {
            #pragma unroll
            for (int j = 0; j < 16; ++j)
                acc[j] = fmaf(ie[k], aW1[(64 + k) * EMB + d0 + j], acc[j]);
        }
        #pragma unroll
        for (int j = 0; j < 16; ++j) {
            float t = tanhf(acc[j]);
            int d = d0 + j;
            s0 = fmaf(t, aW2[d * 3 + 0], s0);
            s1 = fmaf(t, aW2[d * 3 + 1], s1);
            s2 = fmaf(t, aW2[d * 3 + 2], s2);
        }
    }
    float mx = fmaxf(s0, fmaxf(s1, s2));
    float ew0 = expf(s0 - mx), ew1 = expf(s1 - mx), ew2 = expf(s2 - mx);
    float inv = 1.f / (ew0 + ew1 + ew2);
    float w0 = ew0 * inv, w1 = ew1 * inv, w2 = ew2 * inv;

    const float4* r0 = reinterpret_cast<const float4*>(m0 + (size_t)i * EMB);
    const float4* r1 = reinterpret_cast<const float4*>(m1 + (size_t)i * EMB);
    float4* orow = reinterpret_cast<float4*>(e0 + (size_t)(N_USERS + i) * EMB);
    #pragma unroll
    for (int q = 0; q < 16; ++q) {
        float4 a = r0[q], bq = r1[q];
        float4 res;
        res.x = ie[q*4+0] + w0*a.x + w1*bq.x + w2*hdr[192 + q*4+0];
        res.y = ie[q*4+1] + w0*a.y + w1*bq.y + w2*hdr[192 + q*4+1];
        res.z = ie[q*4+2] + w0*a.z + w1*bq.z + w2*hdr[192 + q*4+2];
        res.w = ie[q*4+3] + w0*a.w + w1*bq.w + w2*hdr[192 + q*4+3];
        orow[q] = res;
    }
}

// ---------------------------------------------------------------------------
// CSR build, two-level counting sort (no serial scan, write-combined stores).
// ---------------------------------------------------------------------------
__global__ __launch_bounds__(256) void bucket_hist_kernel(
    const int* __restrict__ rows, int* __restrict__ bktcnt)
{
    __shared__ int h[NBKT];
    int tid = threadIdx.x;
    for (int i = tid; i < NBKT; i += 256) h[i] = 0;
    __syncthreads();
    int stride = gridDim.x * 256;
    for (int i = blockIdx.x * 256 + tid; i < N_EDGES; i += stride)
        atomicAdd(&h[rows[i] >> 8], 1);
    __syncthreads();
    for (int i = tid; i < NBKT; i += 256)
        if (h[i]) atomicAdd(&bktcnt[i], h[i]);
}

// single block: exclusive-scan 586 bucket counts -> gbkt (working) + bstart
__global__ __launch_bounds__(1024) void bucket_scan_kernel(
    const int* __restrict__ bktcnt, int* __restrict__ gbkt,
    int* __restrict__ bstart)
{
    __shared__ int s[1024];
    int t = threadIdx.x;
    int v = (t < NBKT) ? bktcnt[t] : 0;
    s[t] = v;
    __syncthreads();
    for (int off = 1; off < 1024; off <<= 1) {
        int u = (t >= off) ? s[t - off] : 0;
        __syncthreads();
        s[t] += u;
        __syncthreads();
    }
    if (t < NBKT) {
        int excl = s[t] - v;
        gbkt[t] = excl;
        bstart[t] = excl;
    }
    if (t == 0) bstart[NBKT] = N_EDGES;
}

// chunk-per-block scatter into bucket-grouped tmp[] (12B records).
// Per (block,bucket) base via ONE global atomic; positions sequential within
// each bucket stream -> L2 write-combines to full lines.
__global__ __launch_bounds__(256) void bucket_scatter_kernel(
    const int* __restrict__ rows, const int* __restrict__ cols,
    const float* __restrict__ vals, int* __restrict__ gbkt,
    int3* __restrict__ tmp)
{
    __shared__ int lrows[EPB];
    __shared__ int h[NBKT];
    int tid = threadIdx.x;
    int s = blockIdx.x * EPB;
    int e = s + EPB; if (e > N_EDGES) e = N_EDGES;
    int n = e - s;
    for (int i = tid; i < NBKT; i += 256) h[i] = 0;
    __syncthreads();
    for (int i = tid; i < n; i += 256) {
        int r = rows[s + i];
        lrows[i] = r;
        atomicAdd(&h[r >> 8], 1);
    }
    __syncthreads();
    for (int d = tid; d < NBKT; d += 256) {
        int c = h[d];
        h[d] = c ? atomicAdd(&gbkt[d], c) : 0;
    }
    __syncthreads();
    for (int i = tid; i < n; i += 256) {
        int r = lrows[i];
        int p = atomicAdd(&h[r >> 8], 1);
        tmp[p] = make_int3(r, cols[s + i], __float_as_int(vals[s + i]));
    }
}

// bucket-per-block: row-hist -> LDS scan -> offs[] (inclusive prefix) +
// final {col,val} edges within the bucket's contiguous region.
__global__ __launch_bounds__(256) void bucket_to_csr_kernel(
    const int3* __restrict__ tmp, const int* __restrict__ bstart,
    int* __restrict__ offs, int2* __restrict__ edges)
{
    __shared__ int cnt[256], sc[256], pos[256];
    int b = blockIdx.x;
    int t = threadIdx.x;
    int s = bstart[b], e = bstart[b + 1];
    cnt[t] = 0;
    __syncthreads();
    for (int i = s + t; i < e; i += 256)
        atomicAdd(&cnt[tmp[i].x & 255], 1);
    __syncthreads();
    int v = cnt[t];
    sc[t] = v;
    __syncthreads();
    for (int off = 1; off < 256; off <<= 1) {
        int u = (t >= off) ? sc[t - off] : 0;
        __syncthreads();
        sc[t] += u;
        __syncthreads();
    }
    int incl = sc[t];
    int row = (b << 8) + t;
    if (row < N_NODES) offs[row] = s + incl;
    pos[t] = s + incl - v;
    __syncthreads();
    for (int i = s + t; i < e; i += 256) {
        int3 ed = tmp[i];
        int p = atomicAdd(&pos[ed.x & 255], 1);
        edges[p] = make_int2(ed.y, ed.z);
    }
}

// ---------------------------------------------------------------------------
// CSR SpMM: one 64-lane wave per row, lane = dim. Coalesced 256B gathers,
// no atomics. FINAL fuses out = (e0 + e1 + A*e1) / 3.
// ---------------------------------------------------------------------------
template<int FINAL>
__global__ __launch_bounds__(256) void spmm_csr_kernel(
    const int* __restrict__ offs, const int2* __restrict__ edges,
    const float* __restrict__ src, const float* __restrict__ e0,
    const float* __restrict__ e1, float* __restrict__ dst)
{
    int r = __builtin_amdgcn_readfirstlane(blockIdx.x * 4 + (threadIdx.x >> 6));
    if (r >= N_NODES) return;
    int d = threadIdx.x & 63;
    int start = (r == 0) ? 0 : offs[r - 1];
    int end = offs[r];
    float acc0 = 0.f, acc1 = 0.f;
    int i = start;
    for (; i + 2 <= end; i += 2) {
        int2 p0 = edges[i], p1 = edges[i + 1];
        float v0 = __int_as_float(p0.y), v1 = __int_as_float(p1.y);
        acc0 = fmaf(v0, src[(size_t)p0.x * EMB + d], acc0);
        acc1 = fmaf(v1, src[(size_t)p1.x * EMB + d], acc1);
    }
    if (i < end) {
        int2 p = edges[i];
        acc0 = fmaf(__int_as_float(p.y), src[(size_t)p.x * EMB + d], acc0);
    }
    float s = acc0 + acc1;
    size_t idx = (size_t)r * EMB + d;
    if (FINAL)
        dst[idx] = (e0[idx] + e1[idx] + s) * (1.f / 3.f);
    else
        dst[idx] = s;
}

extern "C" void kernel_launch(void* const* d_in, const int* in_sizes, int n_in,
                              void* d_out, int out_size, void* d_ws, size_t ws_size,
                              hipStream_t stream)
{
    const float* user_emb = (const float*)d_in[0];
    const float* item_emb = (const float*)d_in[1];
    const float* mf0 = (const float*)d_in[2];
    const float* mf1 = (const float*)d_in[3];
    const float* mf2 = (const float*)d_in[4];
    const float* W0  = (const float*)d_in[5];
    const float* b0  = (const float*)d_in[6];
    const float* g0  = (const float*)d_in[7];
    const float* be0 = (const float*)d_in[8];
    const float* W1  = (const float*)d_in[9];
    const float* b1  = (const float*)d_in[10];
    const float* g1  = (const float*)d_in[11];
    const float* be1 = (const float*)d_in[12];
    const float* W2  = (const float*)d_in[13];
    const float* b2  = (const float*)d_in[14];
    const float* g2  = (const float*)d_in[15];
    const float* be2 = (const float*)d_in[16];
    const float* aW1 = (const float*)d_in[17];
    const float* ab1 = (const float*)d_in[18];
    const float* aW2 = (const float*)d_in[19];
    const float* ab2 = (const float*)d_in[20];
    const float* avals = (const float*)d_in[21];
    const int* arows = (const int*)d_in[22];
    const int* acols = (const int*)d_in[23];
    float* out = (float*)d_out;

    float* ws  = (float*)d_ws;
    float* hdr = ws;                                   // 512 floats
    float* m0b = ws + 512;                             // 50000*64
    float* m1b = m0b + (size_t)N_ITEMS * EMB;          // 50000*64
    float* e0  = m1b + (size_t)N_ITEMS * EMB;          // 150000*64
    float* e1  = e0 + (size_t)N_NODES * EMB;           // 150000*64
    int*   offs = (int*)(e1 + (size_t)N_NODES * EMB);  // 150000 ints
    int2*  edges = (int2*)(offs + N_NODES);            // 4M int2 (32 MB)
    int*   bktcnt = (int*)(edges + N_EDGES);           // NBKT
    int*   gbkt   = bktcnt + NBKT;                     // NBKT
    int*   bstart = gbkt + NBKT;                       // NBKT+1
    int3*  tmp = (int3*)e0;  // 48MB aliases e0+e1; consumed before e0 written

    hipMemsetAsync(hdr, 0, 128 * sizeof(float), stream);
    hipMemsetAsync(bktcnt, 0, NBKT * sizeof(int), stream);

    // CSR build: two-level counting sort
    bucket_hist_kernel<<<1024, 256, 0, stream>>>(arows, bktcnt);
    bucket_scan_kernel<<<1, 1024, 0, stream>>>(bktcnt, gbkt, bstart);
    bucket_scatter_kernel<<<C_BLOCKS, 256, 0, stream>>>(arows, acols, avals, gbkt, tmp);
    bucket_to_csr_kernel<<<NBKT, 256, 0, stream>>>(tmp, bstart, offs, edges);

    // embedding pipeline (tiled-GEMM encoders, 64x64 tile per block)
    colsum_kernel<<<256, 256, 0, stream>>>(user_emb, N_USERS * EMB, hdr);   // u_sum
    encode_gemm_kernel<128, 0><<<(N_USERS + 63) / 64, 256, 0, stream>>>(
        mf2, W2, b2, g2, be2, nullptr, hdr + 64, N_USERS);                  // um_sum fused
    finalize_kernel<<<1, 64, 0, stream>>>(aW1, ab1, hdr);
    encode_gemm_kernel<768, 1><<<(N_ITEMS + 63) / 64, 256, 0, stream>>>(
        mf0, W0, b0, g0, be0, m0b, nullptr, N_ITEMS);
    encode_gemm_kernel<384, 1><<<(N_ITEMS + 63) / 64, 256, 0, stream>>>(
        mf1, W1, b1, g1, be1, m1b, nullptr, N_ITEMS);
    copy_kernel<<<1024, 256, 0, stream>>>(user_emb, e0, N_USERS * EMB / 4);
    item_fuse_kernel<<<(N_ITEMS + 255) / 256, 256, 0, stream>>>(item_emb, m0b, m1b, hdr, aW1, aW2, ab2, e0);

    // two propagation layers, no atomics
    spmm_csr_kernel<0><<<(N_NODES + 3) / 4, 256, 0, stream>>>(offs, edges, e0, e0, e1, e1);
    spmm_csr_kernel<1><<<(N_NODES + 3) / 4, 256, 0, stream>>>(offs, edges, e1, e0, e1, out);
}

// Round 6
// 796.571 us; speedup vs baseline: 3.1701x; 1.3482x over previous
//
#include <hip/hip_runtime.h>
#include <cstdint>

#define N_USERS 100000
#define N_ITEMS 50000
#define N_NODES (N_USERS + N_ITEMS)
#define EMB 64
#define N_EDGES 4000000
#define LN_EPS 1e-5f

#define NBKT 586          // ceil(N_NODES/256): buckets of 256 rows
#define C_BLOCKS 1024
#define EPB 3907          // ceil(N_EDGES/C_BLOCKS)

// ---------------------------------------------------------------------------
// Tiled-GEMM encoder: y = LeakyReLU(LayerNorm(x @ W + b) * g + be, 0.2)
// Block = 256 threads = 64x64 output tile; K staged in 32-chunks.
// WRITE_OUT=0: skip output, accumulate column sums into colsum[64] (enc2).
// ---------------------------------------------------------------------------
template<int K, int WRITE_OUT>
__global__ __launch_bounds__(256) void encode_gemm_kernel(
    const float* __restrict__ X, const float* __restrict__ W,
    const float* __restrict__ b, const float* __restrict__ g,
    const float* __restrict__ be, float* __restrict__ out,
    float* __restrict__ colsum, int R)
{
    __shared__ float sXT[32][68];
    __shared__ float sW[32][64];
    __shared__ float scs[64];

    int tid = threadIdx.x;
    int tx = tid & 15;
    int ty = tid >> 4;
    int rbase = blockIdx.x * 64;

    int xr = tid >> 2;
    int xc = (tid & 3) * 8;
    int wr = tid >> 3;
    int wc = (tid & 7) * 8;

    int gxrow = rbase + xr; if (gxrow >= R) gxrow = R - 1;
    const float* xsrc = X + (size_t)gxrow * K + xc;

    float4 bv = *reinterpret_cast<const float4*>(&b[tx * 4]);
    float4 gv = *reinterpret_cast<const float4*>(&g[tx * 4]);
    float4 bev = *reinterpret_cast<const float4*>(&be[tx * 4]);

    float acc[4][4];
    #pragma unroll
    for (int i = 0; i < 4; ++i) {
        acc[i][0] = bv.x; acc[i][1] = bv.y; acc[i][2] = bv.z; acc[i][3] = bv.w;
    }

    for (int kc = 0; kc < K; kc += 32) {
        float4 a0 = *reinterpret_cast<const float4*>(xsrc + kc);
        float4 a1 = *reinterpret_cast<const float4*>(xsrc + kc + 4);
        float4 w0 = *reinterpret_cast<const float4*>(&W[(size_t)(kc + wr) * EMB + wc]);
        float4 w1 = *reinterpret_cast<const float4*>(&W[(size_t)(kc + wr) * EMB + wc + 4]);
        __syncthreads();
        sXT[xc + 0][xr] = a0.x; sXT[xc + 1][xr] = a0.y;
        sXT[xc + 2][xr] = a0.z; sXT[xc + 3][xr] = a0.w;
        sXT[xc + 4][xr] = a1.x; sXT[xc + 5][xr] = a1.y;
        sXT[xc + 6][xr] = a1.z; sXT[xc + 7][xr] = a1.w;
        *reinterpret_cast<float4*>(&sW[wr][wc]) = w0;
        *reinterpret_cast<float4*>(&sW[wr][wc + 4]) = w1;
        __syncthreads();
        #pragma unroll
        for (int k = 0; k < 32; ++k) {
            float4 xv = *reinterpret_cast<const float4*>(&sXT[k][ty * 4]);
            float4 wv = *reinterpret_cast<const float4*>(&sW[k][tx * 4]);
            float xs[4] = {xv.x, xv.y, xv.z, xv.w};
            float wsv[4] = {wv.x, wv.y, wv.z, wv.w};
            #pragma unroll
            for (int i = 0; i < 4; ++i)
                #pragma unroll
                for (int j = 0; j < 4; ++j)
                    acc[i][j] = fmaf(xs[i], wsv[j], acc[i][j]);
        }
    }

    float gls[4] = {gv.x, gv.y, gv.z, gv.w};
    float bels[4] = {bev.x, bev.y, bev.z, bev.w};
    float csum[4] = {0.f, 0.f, 0.f, 0.f};
    #pragma unroll
    for (int i = 0; i < 4; ++i) {
        float s = acc[i][0] + acc[i][1] + acc[i][2] + acc[i][3];
        float q = acc[i][0]*acc[i][0] + acc[i][1]*acc[i][1]
                + acc[i][2]*acc[i][2] + acc[i][3]*acc[i][3];
        #pragma unroll
        for (int off = 1; off < 16; off <<= 1) {
            s += __shfl_xor(s, off, 64);
            q += __shfl_xor(q, off, 64);
        }
        float mu = s * (1.f / EMB);
        float var = q * (1.f / EMB) - mu * mu;
        float rs = rsqrtf(var + LN_EPS);
        int row = rbase + ty * 4 + i;
        bool valid = row < R;
        float t[4];
        #pragma unroll
        for (int j = 0; j < 4; ++j) {
            float v = (acc[i][j] - mu) * rs * gls[j] + bels[j];
            t[j] = v > 0.f ? v : 0.2f * v;
        }
        if (WRITE_OUT) {
            if (valid)
                *reinterpret_cast<float4*>(&out[(size_t)row * EMB + tx * 4]) =
                    make_float4(t[0], t[1], t[2], t[3]);
        } else {
            #pragma unroll
            for (int j = 0; j < 4; ++j) csum[j] += valid ? t[j] : 0.f;
        }
    }

    if (!WRITE_OUT) {
        #pragma unroll
        for (int j = 0; j < 4; ++j) {
            csum[j] += __shfl_xor(csum[j], 16, 64);
            csum[j] += __shfl_xor(csum[j], 32, 64);
        }
        if (tid < 64) scs[tid] = 0.f;
        __syncthreads();
        if ((tid & 63) < 16) {
            #pragma unroll
            for (int j = 0; j < 4; ++j) atomicAdd(&scs[tx * 4 + j], csum[j]);
        }
        __syncthreads();
        if (tid < 64) unsafeAtomicAdd(&colsum[tid], scs[tid]);
    }
}

__global__ __launch_bounds__(256) void colsum_kernel(
    const float* __restrict__ X, int n, float* __restrict__ sum)
{
    __shared__ float s[256];
    int tid = threadIdx.x;
    float p = 0.f;
    int stride = gridDim.x * 256;
    for (int i = blockIdx.x * 256 + tid; i < n; i += stride) p += X[i];
    s[tid] = p;
    __syncthreads();
    if (tid < 64)
        unsafeAtomicAdd(&sum[tid], s[tid] + s[tid + 64] + s[tid + 128] + s[tid + 192]);
}

// hdr: [0:64) u_sum [64:128) um_sum [128:192) u_mean [192:256) m2_vec [256:320) pre1
__global__ void finalize_kernel(const float* __restrict__ aW1,
                                const float* __restrict__ ab1,
                                float* __restrict__ hdr)
{
    int d = threadIdx.x; // 64 threads
    float um = hdr[d] * (1.f / N_USERS);
    float m2 = hdr[64 + d] * (1.f / N_USERS);
    hdr[128 + d] = um;
    hdr[192 + d] = m2;
    float acc = ab1[d];
    for (int k = 0; k < EMB; ++k)
        acc = fmaf(hdr[k] * (1.f / N_USERS), aW1[k * EMB + d], acc);
    hdr[256 + d] = acc;
}

__global__ void copy_kernel(const float* __restrict__ a, float* __restrict__ o, int n4)
{
    int i = blockIdx.x * blockDim.x + threadIdx.x;
    int stride = gridDim.x * blockDim.x;
    const float4* A = reinterpret_cast<const float4*>(a);
    float4* O = reinterpret_cast<float4*>(o);
    for (; i < n4; i += stride) O[i] = A[i];
}

// ---------------------------------------------------------------------------
// Blocked item fuse: 64 items per 256-thread block (4x4 per thread).
// GEMM vs LDS-staged aW1[64:128]; tanh; per-row 3-score reduce via shfl;
// softmax; fused modal-weighted output. Same tile layout as encode_gemm.
// ---------------------------------------------------------------------------
__global__ __launch_bounds__(256) void item_fuse_gemm_kernel(
    const float* __restrict__ item_emb, const float* __restrict__ m0,
    const float* __restrict__ m1, const float* __restrict__ hdr,
    const float* __restrict__ aW1, const float* __restrict__ aW2,
    const float* __restrict__ ab2, float* __restrict__ e0)
{
    __shared__ float sIE[64][68];   // [k][row] transposed item tile (+4 pad)
    __shared__ float sW1[64][64];   // [k][col] = aW1[64+k][col]

    int tid = threadIdx.x;
    int tx = tid & 15;
    int ty = tid >> 4;
    int rbase = blockIdx.x * 64;

    // stage: item tile (transposed) + aW1 lower half
    int lr = tid >> 2;              // 0..63
    int lc = (tid & 3) * 16;        // 0,16,32,48
    int grow = rbase + lr; if (grow >= N_ITEMS) grow = N_ITEMS - 1;
    const float4* ier = reinterpret_cast<const float4*>(item_emb + (size_t)grow * EMB + lc);
    const float4* wsrc = reinterpret_cast<const float4*>(aW1 + (size_t)(64 + lr) * EMB + lc);
    #pragma unroll
    for (int q = 0; q < 4; ++q) {
        float4 v = ier[q];
        sIE[lc + q*4 + 0][lr] = v.x; sIE[lc + q*4 + 1][lr] = v.y;
        sIE[lc + q*4 + 2][lr] = v.z; sIE[lc + q*4 + 3][lr] = v.w;
        *reinterpret_cast<float4*>(&sW1[lr][lc + q*4]) = wsrc[q];
    }
    __syncthreads();

    // GEMM: acc[i][j] = pre1[col] + sum_k ie[row][k] * aW1[64+k][col]
    float4 pre = *reinterpret_cast<const float4*>(&hdr[256 + tx * 4]);
    float acc[4][4];
    #pragma unroll
    for (int i = 0; i < 4; ++i) {
        acc[i][0] = pre.x; acc[i][1] = pre.y; acc[i][2] = pre.z; acc[i][3] = pre.w;
    }
    #pragma unroll 8
    for (int k = 0; k < 64; ++k) {
        float4 xv = *reinterpret_cast<const float4*>(&sIE[k][ty * 4]);
        float4 wv = *reinterpret_cast<const float4*>(&sW1[k][tx * 4]);
        float xs[4] = {xv.x, xv.y, xv.z, xv.w};
        float wsv[4] = {wv.x, wv.y, wv.z, wv.w};
        #pragma unroll
        for (int i = 0; i < 4; ++i)
            #pragma unroll
            for (int j = 0; j < 4; ++j)
                acc[i][j] = fmaf(xs[i], wsv[j], acc[i][j]);
    }

    // scores: s[i][r] = sum_col tanh(acc)*aW2[col][r]
    float aw[4][3];
    #pragma unroll
    for (int j = 0; j < 4; ++j) {
        aw[j][0] = aW2[(tx*4 + j)*3 + 0];
        aw[j][1] = aW2[(tx*4 + j)*3 + 1];
        aw[j][2] = aW2[(tx*4 + j)*3 + 2];
    }
    float sc[4][3];
    #pragma unroll
    for (int i = 0; i < 4; ++i) { sc[i][0] = 0.f; sc[i][1] = 0.f; sc[i][2] = 0.f; }
    #pragma unroll
    for (int i = 0; i < 4; ++i)
        #pragma unroll
        for (int j = 0; j < 4; ++j) {
            float t = tanhf(acc[i][j]);
            sc[i][0] = fmaf(t, aw[j][0], sc[i][0]);
            sc[i][1] = fmaf(t, aw[j][1], sc[i][1]);
            sc[i][2] = fmaf(t, aw[j][2], sc[i][2]);
        }
    #pragma unroll
    for (int i = 0; i < 4; ++i)
        #pragma unroll
        for (int r = 0; r < 3; ++r) {
            float v = sc[i][r];
            #pragma unroll
            for (int off = 1; off < 16; off <<= 1) v += __shfl_xor(v, off, 64);
            sc[i][r] = v;
        }

    float b20 = ab2[0], b21 = ab2[1], b22 = ab2[2];
    float4 m2v = *reinterpret_cast<const float4*>(&hdr[192 + tx * 4]);
    float m2s[4] = {m2v.x, m2v.y, m2v.z, m2v.w};

    #pragma unroll
    for (int i = 0; i < 4; ++i) {
        int row = rbase + ty * 4 + i;
        if (row >= N_ITEMS) break;
        float s0 = sc[i][0] + b20, s1 = sc[i][1] + b21, s2 = sc[i][2] + b22;
        float mx = fmaxf(s0, fmaxf(s1, s2));
        float e0w = expf(s0 - mx), e1w = expf(s1 - mx), e2w = expf(s2 - mx);
        float inv = 1.f / (e0w + e1w + e2w);
        float w0 = e0w * inv, w1 = e1w * inv, w2 = e2w * inv;

        float4 a = *reinterpret_cast<const float4*>(&m0[(size_t)row * EMB + tx * 4]);
        float4 bq = *reinterpret_cast<const float4*>(&m1[(size_t)row * EMB + tx * 4]);
        int lrow = ty * 4 + i;
        float res[4];
        #pragma unroll
        for (int j = 0; j < 4; ++j) {
            float ie = sIE[tx * 4 + j][lrow];
            float mm = (j == 0 ? a.x : j == 1 ? a.y : j == 2 ? a.z : a.w);
            float m1e = (j == 0 ? bq.x : j == 1 ? bq.y : j == 2 ? bq.z : bq.w);
            res[j] = ie + w0 * mm + w1 * m1e + w2 * m2s[j];
        }
        *reinterpret_cast<float4*>(&e0[(size_t)(N_USERS + row) * EMB + tx * 4]) =
            make_float4(res[0], res[1], res[2], res[3]);
    }
}

// ---------------------------------------------------------------------------
// CSR build, two-level counting sort (no serial scan, write-combined stores).
// ---------------------------------------------------------------------------
__global__ __launch_bounds__(256) void bucket_hist_kernel(
    const int* __restrict__ rows, int* __restrict__ bktcnt)
{
    __shared__ int h[NBKT];
    int tid = threadIdx.x;
    for (int i = tid; i < NBKT; i += 256) h[i] = 0;
    __syncthreads();
    int stride = gridDim.x * 256;
    for (int i = blockIdx.x * 256 + tid; i < N_EDGES; i += stride)
        atomicAdd(&h[rows[i] >> 8], 1);
    __syncthreads();
    for (int i = tid; i < NBKT; i += 256)
        if (h[i]) atomicAdd(&bktcnt[i], h[i]);
}

// single block: exclusive-scan 586 bucket counts -> gbkt (working) + bstart
__global__ __launch_bounds__(1024) void bucket_scan_kernel(
    const int* __restrict__ bktcnt, int* __restrict__ gbkt,
    int* __restrict__ bstart)
{
    __shared__ int s[1024];
    int t = threadIdx.x;
    int v = (t < NBKT) ? bktcnt[t] : 0;
    s[t] = v;
    __syncthreads();
    for (int off = 1; off < 1024; off <<= 1) {
        int u = (t >= off) ? s[t - off] : 0;
        __syncthreads();
        s[t] += u;
        __syncthreads();
    }
    if (t < NBKT) {
        int excl = s[t] - v;
        gbkt[t] = excl;
        bstart[t] = excl;
    }
    if (t == 0) bstart[NBKT] = N_EDGES;
}

// chunk-per-block scatter into bucket-grouped tmp[] (12B records).
__global__ __launch_bounds__(256) void bucket_scatter_kernel(
    const int* __restrict__ rows, const int* __restrict__ cols,
    const float* __restrict__ vals, int* __restrict__ gbkt,
    int3* __restrict__ tmp)
{
    __shared__ int lrows[EPB];
    __shared__ int h[NBKT];
    int tid = threadIdx.x;
    int s = blockIdx.x * EPB;
    int e = s + EPB; if (e > N_EDGES) e = N_EDGES;
    int n = e - s;
    for (int i = tid; i < NBKT; i += 256) h[i] = 0;
    __syncthreads();
    for (int i = tid; i < n; i += 256) {
        int r = rows[s + i];
        lrows[i] = r;
        atomicAdd(&h[r >> 8], 1);
    }
    __syncthreads();
    for (int d = tid; d < NBKT; d += 256) {
        int c = h[d];
        h[d] = c ? atomicAdd(&gbkt[d], c) : 0;
    }
    __syncthreads();
    for (int i = tid; i < n; i += 256) {
        int r = lrows[i];
        int p = atomicAdd(&h[r >> 8], 1);
        tmp[p] = make_int3(r, cols[s + i], __float_as_int(vals[s + i]));
    }
}

// bucket-per-block: row-hist -> LDS scan -> offs[] (inclusive prefix) +
// final {col,val} edges within the bucket's contiguous region.
__global__ __launch_bounds__(256) void bucket_to_csr_kernel(
    const int3* __restrict__ tmp, const int* __restrict__ bstart,
    int* __restrict__ offs, int2* __restrict__ edges)
{
    __shared__ int cnt[256], sc[256], pos[256];
    int b = blockIdx.x;
    int t = threadIdx.x;
    int s = bstart[b], e = bstart[b + 1];
    cnt[t] = 0;
    __syncthreads();
    for (int i = s + t; i < e; i += 256)
        atomicAdd(&cnt[tmp[i].x & 255], 1);
    __syncthreads();
    int v = cnt[t];
    sc[t] = v;
    __syncthreads();
    for (int off = 1; off < 256; off <<= 1) {
        int u = (t >= off) ? sc[t - off] : 0;
        __syncthreads();
        sc[t] += u;
        __syncthreads();
    }
    int incl = sc[t];
    int row = (b << 8) + t;
    if (row < N_NODES) offs[row] = s + incl;
    pos[t] = s + incl - v;
    __syncthreads();
    for (int i = s + t; i < e; i += 256) {
        int3 ed = tmp[i];
        int p = atomicAdd(&pos[ed.x & 255], 1);
        edges[p] = make_int2(ed.y, ed.z);
    }
}

// ---------------------------------------------------------------------------
// CSR SpMM: one 64-lane wave per row, lane = dim. Coalesced 256B gathers,
// no atomics. FINAL fuses out = (e0 + e1 + A*e1) / 3.
// ---------------------------------------------------------------------------
template<int FINAL>
__global__ __launch_bounds__(256) void spmm_csr_kernel(
    const int* __restrict__ offs, const int2* __restrict__ edges,
    const float* __restrict__ src, const float* __restrict__ e0,
    const float* __restrict__ e1, float* __restrict__ dst)
{
    int r = __builtin_amdgcn_readfirstlane(blockIdx.x * 4 + (threadIdx.x >> 6));
    if (r >= N_NODES) return;
    int d = threadIdx.x & 63;
    int start = (r == 0) ? 0 : offs[r - 1];
    int end = offs[r];
    float acc0 = 0.f, acc1 = 0.f;
    int i = start;
    for (; i + 2 <= end; i += 2) {
        int2 p0 = edges[i], p1 = edges[i + 1];
        float v0 = __int_as_float(p0.y), v1 = __int_as_float(p1.y);
        acc0 = fmaf(v0, src[(size_t)p0.x * EMB + d], acc0);
        acc1 = fmaf(v1, src[(size_t)p1.x * EMB + d], acc1);
    }
    if (i < end) {
        int2 p = edges[i];
        acc0 = fmaf(__int_as_float(p.y), src[(size_t)p.x * EMB + d], acc0);
    }
    float s = acc0 + acc1;
    size_t idx = (size_t)r * EMB + d;
    if (FINAL)
        dst[idx] = (e0[idx] + e1[idx] + s) * (1.f / 3.f);
    else
        dst[idx] = s;
}

extern "C" void kernel_launch(void* const* d_in, const int* in_sizes, int n_in,
                              void* d_out, int out_size, void* d_ws, size_t ws_size,
                              hipStream_t stream)
{
    const float* user_emb = (const float*)d_in[0];
    const float* item_emb = (const float*)d_in[1];
    const float* mf0 = (const float*)d_in[2];
    const float* mf1 = (const float*)d_in[3];
    const float* mf2 = (const float*)d_in[4];
    const float* W0  = (const float*)d_in[5];
    const float* b0  = (const float*)d_in[6];
    const float* g0  = (const float*)d_in[7];
    const float* be0 = (const float*)d_in[8];
    const float* W1  = (const float*)d_in[9];
    const float* b1  = (const float*)d_in[10];
    const float* g1  = (const float*)d_in[11];
    const float* be1 = (const float*)d_in[12];
    const float* W2  = (const float*)d_in[13];
    const float* b2  = (const float*)d_in[14];
    const float* g2  = (const float*)d_in[15];
    const float* be2 = (const float*)d_in[16];
    const float* aW1 = (const float*)d_in[17];
    const float* ab1 = (const float*)d_in[18];
    const float* aW2 = (const float*)d_in[19];
    const float* ab2 = (const float*)d_in[20];
    const float* avals = (const float*)d_in[21];
    const int* arows = (const int*)d_in[22];
    const int* acols = (const int*)d_in[23];
    float* out = (float*)d_out;

    float* ws  = (float*)d_ws;
    float* hdr = ws;                                   // 512 floats
    float* m0b = ws + 512;                             // 50000*64
    float* m1b = m0b + (size_t)N_ITEMS * EMB;          // 50000*64
    float* e0  = m1b + (size_t)N_ITEMS * EMB;          // 150000*64
    float* e1  = e0 + (size_t)N_NODES * EMB;           // 150000*64
    int*   offs = (int*)(e1 + (size_t)N_NODES * EMB);  // 150000 ints
    int2*  edges = (int2*)(offs + N_NODES);            // 4M int2 (32 MB)
    int*   bktcnt = (int*)(edges + N_EDGES);           // NBKT
    int*   gbkt   = bktcnt + NBKT;                     // NBKT
    int*   bstart = gbkt + NBKT;                       // NBKT+1
    int3*  tmp = (int3*)e0;  // 48MB aliases e0+e1; consumed before e0 written

    hipMemsetAsync(hdr, 0, 128 * sizeof(float), stream);
    hipMemsetAsync(bktcnt, 0, NBKT * sizeof(int), stream);

    // CSR build: two-level counting sort
    bucket_hist_kernel<<<1024, 256, 0, stream>>>(arows, bktcnt);
    bucket_scan_kernel<<<1, 1024, 0, stream>>>(bktcnt, gbkt, bstart);
    bucket_scatter_kernel<<<C_BLOCKS, 256, 0, stream>>>(arows, acols, avals, gbkt, tmp);
    bucket_to_csr_kernel<<<NBKT, 256, 0, stream>>>(tmp, bstart, offs, edges);

    // embedding pipeline (tiled-GEMM encoders, 64x64 tile per block)
    colsum_kernel<<<256, 256, 0, stream>>>(user_emb, N_USERS * EMB, hdr);   // u_sum
    encode_gemm_kernel<128, 0><<<(N_USERS + 63) / 64, 256, 0, stream>>>(
        mf2, W2, b2, g2, be2, nullptr, hdr + 64, N_USERS);                  // um_sum fused
    finalize_kernel<<<1, 64, 0, stream>>>(aW1, ab1, hdr);
    encode_gemm_kernel<768, 1><<<(N_ITEMS + 63) / 64, 256, 0, stream>>>(
        mf0, W0, b0, g0, be0, m0b, nullptr, N_ITEMS);
    encode_gemm_kernel<384, 1><<<(N_ITEMS + 63) / 64, 256, 0, stream>>>(
        mf1, W1, b1, g1, be1, m1b, nullptr, N_ITEMS);
    copy_kernel<<<1024, 256, 0, stream>>>(user_emb, e0, N_USERS * EMB / 4);
    item_fuse_gemm_kernel<<<(N_ITEMS + 63) / 64, 256, 0, stream>>>(
        item_emb, m0b, m1b, hdr, aW1, aW2, ab2, e0);

    // two propagation layers, no atomics
    spmm_csr_kernel<0><<<(N_NODES + 3) / 4, 256, 0, stream>>>(offs, edges, e0, e0, e1, e1);
    spmm_csr_kernel<1><<<(N_NODES + 3) / 4, 256, 0, stream>>>(offs, edges, e1, e0, e1, out);
}

// Round 7
// 752.359 us; speedup vs baseline: 3.3564x; 1.0588x over previous
//
#include <hip/hip_runtime.h>
#include <cstdint>

#define N_USERS 100000
#define N_ITEMS 50000
#define N_NODES (N_USERS + N_ITEMS)
#define EMB 64
#define N_EDGES 4000000
#define LN_EPS 1e-5f

#define NBKT 586          // ceil(N_NODES/256): buckets of 256 rows
#define C_BLOCKS 1024
#define EPB 3907          // ceil(N_EDGES/C_BLOCKS)

// ---------------------------------------------------------------------------
// Tiled-GEMM encoder: y = LeakyReLU(LayerNorm(x @ W + b) * g + be, 0.2)
// Block = 256 threads = 64x64 output tile; K staged in 32-chunks.
// WRITE_OUT=0: skip output, accumulate column sums into colsum[64] (enc2).
// ---------------------------------------------------------------------------
template<int K, int WRITE_OUT>
__global__ __launch_bounds__(256) void encode_gemm_kernel(
    const float* __restrict__ X, const float* __restrict__ W,
    const float* __restrict__ b, const float* __restrict__ g,
    const float* __restrict__ be, float* __restrict__ out,
    float* __restrict__ colsum, int R)
{
    __shared__ float sXT[32][68];
    __shared__ float sW[32][64];
    __shared__ float scs[64];

    int tid = threadIdx.x;
    int tx = tid & 15;
    int ty = tid >> 4;
    int rbase = blockIdx.x * 64;

    int xr = tid >> 2;
    int xc = (tid & 3) * 8;
    int wr = tid >> 3;
    int wc = (tid & 7) * 8;

    int gxrow = rbase + xr; if (gxrow >= R) gxrow = R - 1;
    const float* xsrc = X + (size_t)gxrow * K + xc;

    float4 bv = *reinterpret_cast<const float4*>(&b[tx * 4]);
    float4 gv = *reinterpret_cast<const float4*>(&g[tx * 4]);
    float4 bev = *reinterpret_cast<const float4*>(&be[tx * 4]);

    float acc[4][4];
    #pragma unroll
    for (int i = 0; i < 4; ++i) {
        acc[i][0] = bv.x; acc[i][1] = bv.y; acc[i][2] = bv.z; acc[i][3] = bv.w;
    }

    for (int kc = 0; kc < K; kc += 32) {
        float4 a0 = *reinterpret_cast<const float4*>(xsrc + kc);
        float4 a1 = *reinterpret_cast<const float4*>(xsrc + kc + 4);
        float4 w0 = *reinterpret_cast<const float4*>(&W[(size_t)(kc + wr) * EMB + wc]);
        float4 w1 = *reinterpret_cast<const float4*>(&W[(size_t)(kc + wr) * EMB + wc + 4]);
        __syncthreads();
        sXT[xc + 0][xr] = a0.x; sXT[xc + 1][xr] = a0.y;
        sXT[xc + 2][xr] = a0.z; sXT[xc + 3][xr] = a0.w;
        sXT[xc + 4][xr] = a1.x; sXT[xc + 5][xr] = a1.y;
        sXT[xc + 6][xr] = a1.z; sXT[xc + 7][xr] = a1.w;
        *reinterpret_cast<float4*>(&sW[wr][wc]) = w0;
        *reinterpret_cast<float4*>(&sW[wr][wc + 4]) = w1;
        __syncthreads();
        #pragma unroll
        for (int k = 0; k < 32; ++k) {
            float4 xv = *reinterpret_cast<const float4*>(&sXT[k][ty * 4]);
            float4 wv = *reinterpret_cast<const float4*>(&sW[k][tx * 4]);
            float xs[4] = {xv.x, xv.y, xv.z, xv.w};
            float wsv[4] = {wv.x, wv.y, wv.z, wv.w};
            #pragma unroll
            for (int i = 0; i < 4; ++i)
                #pragma unroll
                for (int j = 0; j < 4; ++j)
                    acc[i][j] = fmaf(xs[i], wsv[j], acc[i][j]);
        }
    }

    float gls[4] = {gv.x, gv.y, gv.z, gv.w};
    float bels[4] = {bev.x, bev.y, bev.z, bev.w};
    float csum[4] = {0.f, 0.f, 0.f, 0.f};
    #pragma unroll
    for (int i = 0; i < 4; ++i) {
        float s = acc[i][0] + acc[i][1] + acc[i][2] + acc[i][3];
        float q = acc[i][0]*acc[i][0] + acc[i][1]*acc[i][1]
                + acc[i][2]*acc[i][2] + acc[i][3]*acc[i][3];
        #pragma unroll
        for (int off = 1; off < 16; off <<= 1) {
            s += __shfl_xor(s, off, 64);
            q += __shfl_xor(q, off, 64);
        }
        float mu = s * (1.f / EMB);
        float var = q * (1.f / EMB) - mu * mu;
        float rs = rsqrtf(var + LN_EPS);
        int row = rbase + ty * 4 + i;
        bool valid = row < R;
        float t[4];
        #pragma unroll
        for (int j = 0; j < 4; ++j) {
            float v = (acc[i][j] - mu) * rs * gls[j] + bels[j];
            t[j] = v > 0.f ? v : 0.2f * v;
        }
        if (WRITE_OUT) {
            if (valid)
                *reinterpret_cast<float4*>(&out[(size_t)row * EMB + tx * 4]) =
                    make_float4(t[0], t[1], t[2], t[3]);
        } else {
            #pragma unroll
            for (int j = 0; j < 4; ++j) csum[j] += valid ? t[j] : 0.f;
        }
    }

    if (!WRITE_OUT) {
        #pragma unroll
        for (int j = 0; j < 4; ++j) {
            csum[j] += __shfl_xor(csum[j], 16, 64);
            csum[j] += __shfl_xor(csum[j], 32, 64);
        }
        if (tid < 64) scs[tid] = 0.f;
        __syncthreads();
        if ((tid & 63) < 16) {
            #pragma unroll
            for (int j = 0; j < 4; ++j) atomicAdd(&scs[tx * 4 + j], csum[j]);
        }
        __syncthreads();
        if (tid < 64) unsafeAtomicAdd(&colsum[tid], scs[tid]);
    }
}

__global__ __launch_bounds__(256) void colsum_kernel(
    const float* __restrict__ X, int n, float* __restrict__ sum)
{
    __shared__ float s[256];
    int tid = threadIdx.x;
    float p = 0.f;
    int stride = gridDim.x * 256;
    for (int i = blockIdx.x * 256 + tid; i < n; i += stride) p += X[i];
    s[tid] = p;
    __syncthreads();
    if (tid < 64)
        unsafeAtomicAdd(&sum[tid], s[tid] + s[tid + 64] + s[tid + 128] + s[tid + 192]);
}

// hdr: [0:64) u_sum [64:128) um_sum [128:192) u_mean [192:256) m2_vec [256:320) pre1
__global__ void finalize_kernel(const float* __restrict__ aW1,
                                const float* __restrict__ ab1,
                                float* __restrict__ hdr)
{
    int d = threadIdx.x; // 64 threads
    float um = hdr[d] * (1.f / N_USERS);
    float m2 = hdr[64 + d] * (1.f / N_USERS);
    hdr[128 + d] = um;
    hdr[192 + d] = m2;
    float acc = ab1[d];
    for (int k = 0; k < EMB; ++k)
        acc = fmaf(hdr[k] * (1.f / N_USERS), aW1[k * EMB + d], acc);
    hdr[256 + d] = acc;
}

__global__ void copy_kernel(const float* __restrict__ a, float* __restrict__ o, int n4)
{
    int i = blockIdx.x * blockDim.x + threadIdx.x;
    int stride = gridDim.x * blockDim.x;
    const float4* A = reinterpret_cast<const float4*>(a);
    float4* O = reinterpret_cast<float4*>(o);
    for (; i < n4; i += stride) O[i] = A[i];
}

// ---------------------------------------------------------------------------
// Blocked item fuse: 64 items per 256-thread block (4x4 per thread).
// ---------------------------------------------------------------------------
__global__ __launch_bounds__(256) void item_fuse_gemm_kernel(
    const float* __restrict__ item_emb, const float* __restrict__ m0,
    const float* __restrict__ m1, const float* __restrict__ hdr,
    const float* __restrict__ aW1, const float* __restrict__ aW2,
    const float* __restrict__ ab2, float* __restrict__ e0)
{
    __shared__ float sIE[64][68];   // [k][row] transposed item tile (+4 pad)
    __shared__ float sW1[64][64];   // [k][col] = aW1[64+k][col]

    int tid = threadIdx.x;
    int tx = tid & 15;
    int ty = tid >> 4;
    int rbase = blockIdx.x * 64;

    int lr = tid >> 2;              // 0..63
    int lc = (tid & 3) * 16;        // 0,16,32,48
    int grow = rbase + lr; if (grow >= N_ITEMS) grow = N_ITEMS - 1;
    const float4* ier = reinterpret_cast<const float4*>(item_emb + (size_t)grow * EMB + lc);
    const float4* wsrc = reinterpret_cast<const float4*>(aW1 + (size_t)(64 + lr) * EMB + lc);
    #pragma unroll
    for (int q = 0; q < 4; ++q) {
        float4 v = ier[q];
        sIE[lc + q*4 + 0][lr] = v.x; sIE[lc + q*4 + 1][lr] = v.y;
        sIE[lc + q*4 + 2][lr] = v.z; sIE[lc + q*4 + 3][lr] = v.w;
        *reinterpret_cast<float4*>(&sW1[lr][lc + q*4]) = wsrc[q];
    }
    __syncthreads();

    float4 pre = *reinterpret_cast<const float4*>(&hdr[256 + tx * 4]);
    float acc[4][4];
    #pragma unroll
    for (int i = 0; i < 4; ++i) {
        acc[i][0] = pre.x; acc[i][1] = pre.y; acc[i][2] = pre.z; acc[i][3] = pre.w;
    }
    #pragma unroll 8
    for (int k = 0; k < 64; ++k) {
        float4 xv = *reinterpret_cast<const float4*>(&sIE[k][ty * 4]);
        float4 wv = *reinterpret_cast<const float4*>(&sW1[k][tx * 4]);
        float xs[4] = {xv.x, xv.y, xv.z, xv.w};
        float wsv[4] = {wv.x, wv.y, wv.z, wv.w};
        #pragma unroll
        for (int i = 0; i < 4; ++i)
            #pragma unroll
            for (int j = 0; j < 4; ++j)
                acc[i][j] = fmaf(xs[i], wsv[j], acc[i][j]);
    }

    float aw[4][3];
    #pragma unroll
    for (int j = 0; j < 4; ++j) {
        aw[j][0] = aW2[(tx*4 + j)*3 + 0];
        aw[j][1] = aW2[(tx*4 + j)*3 + 1];
        aw[j][2] = aW2[(tx*4 + j)*3 + 2];
    }
    float sc[4][3];
    #pragma unroll
    for (int i = 0; i < 4; ++i) { sc[i][0] = 0.f; sc[i][1] = 0.f; sc[i][2] = 0.f; }
    #pragma unroll
    for (int i = 0; i < 4; ++i)
        #pragma unroll
        for (int j = 0; j < 4; ++j) {
            float t = tanhf(acc[i][j]);
            sc[i][0] = fmaf(t, aw[j][0], sc[i][0]);
            sc[i][1] = fmaf(t, aw[j][1], sc[i][1]);
            sc[i][2] = fmaf(t, aw[j][2], sc[i][2]);
        }
    #pragma unroll
    for (int i = 0; i < 4; ++i)
        #pragma unroll
        for (int r = 0; r < 3; ++r) {
            float v = sc[i][r];
            #pragma unroll
            for (int off = 1; off < 16; off <<= 1) v += __shfl_xor(v, off, 64);
            sc[i][r] = v;
        }

    float b20 = ab2[0], b21 = ab2[1], b22 = ab2[2];
    float4 m2v = *reinterpret_cast<const float4*>(&hdr[192 + tx * 4]);
    float m2s[4] = {m2v.x, m2v.y, m2v.z, m2v.w};

    #pragma unroll
    for (int i = 0; i < 4; ++i) {
        int row = rbase + ty * 4 + i;
        if (row >= N_ITEMS) break;
        float s0 = sc[i][0] + b20, s1 = sc[i][1] + b21, s2 = sc[i][2] + b22;
        float mx = fmaxf(s0, fmaxf(s1, s2));
        float e0w = expf(s0 - mx), e1w = expf(s1 - mx), e2w = expf(s2 - mx);
        float inv = 1.f / (e0w + e1w + e2w);
        float w0 = e0w * inv, w1 = e1w * inv, w2 = e2w * inv;

        float4 a = *reinterpret_cast<const float4*>(&m0[(size_t)row * EMB + tx * 4]);
        float4 bq = *reinterpret_cast<const float4*>(&m1[(size_t)row * EMB + tx * 4]);
        int lrow = ty * 4 + i;
        float res[4];
        #pragma unroll
        for (int j = 0; j < 4; ++j) {
            float ie = sIE[tx * 4 + j][lrow];
            float mm = (j == 0 ? a.x : j == 1 ? a.y : j == 2 ? a.z : a.w);
            float m1e = (j == 0 ? bq.x : j == 1 ? bq.y : j == 2 ? bq.z : bq.w);
            res[j] = ie + w0 * mm + w1 * m1e + w2 * m2s[j];
        }
        *reinterpret_cast<float4*>(&e0[(size_t)(N_USERS + row) * EMB + tx * 4]) =
            make_float4(res[0], res[1], res[2], res[3]);
    }
}

// ---------------------------------------------------------------------------
// CSR build, two-level counting sort (no serial scan, write-combined stores).
// ---------------------------------------------------------------------------
__global__ __launch_bounds__(256) void bucket_hist_kernel(
    const int* __restrict__ rows, int* __restrict__ bktcnt)
{
    __shared__ int h[NBKT];
    int tid = threadIdx.x;
    for (int i = tid; i < NBKT; i += 256) h[i] = 0;
    __syncthreads();
    int stride = gridDim.x * 256;
    for (int i = blockIdx.x * 256 + tid; i < N_EDGES; i += stride)
        atomicAdd(&h[rows[i] >> 8], 1);
    __syncthreads();
    for (int i = tid; i < NBKT; i += 256)
        if (h[i]) atomicAdd(&bktcnt[i], h[i]);
}

// single block: exclusive-scan 586 bucket counts -> gbkt (working) + bstart
__global__ __launch_bounds__(1024) void bucket_scan_kernel(
    const int* __restrict__ bktcnt, int* __restrict__ gbkt,
    int* __restrict__ bstart)
{
    __shared__ int s[1024];
    int t = threadIdx.x;
    int v = (t < NBKT) ? bktcnt[t] : 0;
    s[t] = v;
    __syncthreads();
    for (int off = 1; off < 1024; off <<= 1) {
        int u = (t >= off) ? s[t - off] : 0;
        __syncthreads();
        s[t] += u;
        __syncthreads();
    }
    if (t < NBKT) {
        int excl = s[t] - v;
        gbkt[t] = excl;
        bstart[t] = excl;
    }
    if (t == 0) bstart[NBKT] = N_EDGES;
}

// chunk-per-block scatter into bucket-grouped tmp[] (12B records).
__global__ __launch_bounds__(256) void bucket_scatter_kernel(
    const int* __restrict__ rows, const int* __restrict__ cols,
    const float* __restrict__ vals, int* __restrict__ gbkt,
    int3* __restrict__ tmp)
{
    __shared__ int lrows[EPB];
    __shared__ int h[NBKT];
    int tid = threadIdx.x;
    int s = blockIdx.x * EPB;
    int e = s + EPB; if (e > N_EDGES) e = N_EDGES;
    int n = e - s;
    for (int i = tid; i < NBKT; i += 256) h[i] = 0;
    __syncthreads();
    for (int i = tid; i < n; i += 256) {
        int r = rows[s + i];
        lrows[i] = r;
        atomicAdd(&h[r >> 8], 1);
    }
    __syncthreads();
    for (int d = tid; d < NBKT; d += 256) {
        int c = h[d];
        h[d] = c ? atomicAdd(&gbkt[d], c) : 0;
    }
    __syncthreads();
    for (int i = tid; i < n; i += 256) {
        int r = lrows[i];
        int p = atomicAdd(&h[r >> 8], 1);
        tmp[p] = make_int3(r, cols[s + i], __float_as_int(vals[s + i]));
    }
}

// bucket-per-block: row-hist -> LDS scan -> offs[] (inclusive prefix) +
// final {col,val} edges within the bucket's contiguous region.
__global__ __launch_bounds__(256) void bucket_to_csr_kernel(
    const int3* __restrict__ tmp, const int* __restrict__ bstart,
    int* __restrict__ offs, int2* __restrict__ edges)
{
    __shared__ int cnt[256], sc[256], pos[256];
    int b = blockIdx.x;
    int t = threadIdx.x;
    int s = bstart[b], e = bstart[b + 1];
    cnt[t] = 0;
    __syncthreads();
    for (int i = s + t; i < e; i += 256)
        atomicAdd(&cnt[tmp[i].x & 255], 1);
    __syncthreads();
    int v = cnt[t];
    sc[t] = v;
    __syncthreads();
    for (int off = 1; off < 256; off <<= 1) {
        int u = (t >= off) ? sc[t - off] : 0;
        __syncthreads();
        sc[t] += u;
        __syncthreads();
    }
    int incl = sc[t];
    int row = (b << 8) + t;
    if (row < N_NODES) offs[row] = s + incl;
    pos[t] = s + incl - v;
    __syncthreads();
    for (int i = s + t; i < e; i += 256) {
        int3 ed = tmp[i];
        int p = atomicAdd(&pos[ed.x & 255], 1);
        edges[p] = make_int2(ed.y, ed.z);
    }
}

// ---------------------------------------------------------------------------
// CSR SpMM: one 64-lane wave per row, lane = dim. 4-deep unrolled gathers
// (MLP: ~4x256B in flight per wave); nt loads for the one-touch edge stream
// and nt stores for dst so L3 retains the reused src rows. No atomics.
// FINAL fuses out = (e0 + e1 + A*e1) / 3.
// ---------------------------------------------------------------------------
template<int FINAL>
__global__ __launch_bounds__(256) void spmm_csr_kernel(
    const int* __restrict__ offs, const int2* __restrict__ edges,
    const float* __restrict__ src, const float* __restrict__ e0,
    const float* __restrict__ e1, float* __restrict__ dst)
{
    int r = __builtin_amdgcn_readfirstlane(blockIdx.x * 4 + (threadIdx.x >> 6));
    if (r >= N_NODES) return;
    int d = threadIdx.x & 63;
    int start = __builtin_amdgcn_readfirstlane((r == 0) ? 0 : offs[r - 1]);
    int end = __builtin_amdgcn_readfirstlane(offs[r]);
    const unsigned long long* ep = reinterpret_cast<const unsigned long long*>(edges);

    float a0 = 0.f, a1 = 0.f, a2 = 0.f, a3 = 0.f;
    int i = start;
    for (; i + 4 <= end; i += 4) {
        unsigned long long q0 = __builtin_nontemporal_load(ep + i + 0);
        unsigned long long q1 = __builtin_nontemporal_load(ep + i + 1);
        unsigned long long q2 = __builtin_nontemporal_load(ep + i + 2);
        unsigned long long q3 = __builtin_nontemporal_load(ep + i + 3);
        int c0 = (int)(unsigned)q0; float v0 = __uint_as_float((unsigned)(q0 >> 32));
        int c1 = (int)(unsigned)q1; float v1 = __uint_as_float((unsigned)(q1 >> 32));
        int c2 = (int)(unsigned)q2; float v2 = __uint_as_float((unsigned)(q2 >> 32));
        int c3 = (int)(unsigned)q3; float v3 = __uint_as_float((unsigned)(q3 >> 32));
        float x0 = src[(size_t)c0 * EMB + d];
        float x1 = src[(size_t)c1 * EMB + d];
        float x2 = src[(size_t)c2 * EMB + d];
        float x3 = src[(size_t)c3 * EMB + d];
        a0 = fmaf(v0, x0, a0);
        a1 = fmaf(v1, x1, a1);
        a2 = fmaf(v2, x2, a2);
        a3 = fmaf(v3, x3, a3);
    }
    for (; i < end; ++i) {
        unsigned long long q = __builtin_nontemporal_load(ep + i);
        int c = (int)(unsigned)q; float v = __uint_as_float((unsigned)(q >> 32));
        a0 = fmaf(v, src[(size_t)c * EMB + d], a0);
    }
    float s = (a0 + a1) + (a2 + a3);
    size_t idx = (size_t)r * EMB + d;
    if (FINAL) {
        float v0 = __builtin_nontemporal_load(&e0[idx]);
        float v1 = e1[idx];
        __builtin_nontemporal_store((v0 + v1 + s) * (1.f / 3.f), &dst[idx]);
    } else {
        __builtin_nontemporal_store(s, &dst[idx]);
    }
}

extern "C" void kernel_launch(void* const* d_in, const int* in_sizes, int n_in,
                              void* d_out, int out_size, void* d_ws, size_t ws_size,
                              hipStream_t stream)
{
    const float* user_emb = (const float*)d_in[0];
    const float* item_emb = (const float*)d_in[1];
    const float* mf0 = (const float*)d_in[2];
    const float* mf1 = (const float*)d_in[3];
    const float* mf2 = (const float*)d_in[4];
    const float* W0  = (const float*)d_in[5];
    const float* b0  = (const float*)d_in[6];
    const float* g0  = (const float*)d_in[7];
    const float* be0 = (const float*)d_in[8];
    const float* W1  = (const float*)d_in[9];
    const float* b1  = (const float*)d_in[10];
    const float* g1  = (const float*)d_in[11];
    const float* be1 = (const float*)d_in[12];
    const float* W2  = (const float*)d_in[13];
    const float* b2  = (const float*)d_in[14];
    const float* g2  = (const float*)d_in[15];
    const float* be2 = (const float*)d_in[16];
    const float* aW1 = (const float*)d_in[17];
    const float* ab1 = (const float*)d_in[18];
    const float* aW2 = (const float*)d_in[19];
    const float* ab2 = (const float*)d_in[20];
    const float* avals = (const float*)d_in[21];
    const int* arows = (const int*)d_in[22];
    const int* acols = (const int*)d_in[23];
    float* out = (float*)d_out;

    float* ws  = (float*)d_ws;
    float* hdr = ws;                                   // 512 floats
    float* m0b = ws + 512;                             // 50000*64
    float* m1b = m0b + (size_t)N_ITEMS * EMB;          // 50000*64
    float* e0  = m1b + (size_t)N_ITEMS * EMB;          // 150000*64
    float* e1  = e0 + (size_t)N_NODES * EMB;           // 150000*64
    int*   offs = (int*)(e1 + (size_t)N_NODES * EMB);  // 150000 ints
    int2*  edges = (int2*)(offs + N_NODES);            // 4M int2 (32 MB)
    int*   bktcnt = (int*)(edges + N_EDGES);           // NBKT
    int*   gbkt   = bktcnt + NBKT;                     // NBKT
    int*   bstart = gbkt + NBKT;                       // NBKT+1
    int3*  tmp = (int3*)e0;  // 48MB aliases e0+e1; consumed before e0 written

    hipMemsetAsync(hdr, 0, 128 * sizeof(float), stream);
    hipMemsetAsync(bktcnt, 0, NBKT * sizeof(int), stream);

    // CSR build: two-level counting sort
    bucket_hist_kernel<<<1024, 256, 0, stream>>>(arows, bktcnt);
    bucket_scan_kernel<<<1, 1024, 0, stream>>>(bktcnt, gbkt, bstart);
    bucket_scatter_kernel<<<C_BLOCKS, 256, 0, stream>>>(arows, acols, avals, gbkt, tmp);
    bucket_to_csr_kernel<<<NBKT, 256, 0, stream>>>(tmp, bstart, offs, edges);

    // embedding pipeline (tiled-GEMM encoders, 64x64 tile per block)
    colsum_kernel<<<256, 256, 0, stream>>>(user_emb, N_USERS * EMB, hdr);   // u_sum
    encode_gemm_kernel<128, 0><<<(N_USERS + 63) / 64, 256, 0, stream>>>(
        mf2, W2, b2, g2, be2, nullptr, hdr + 64, N_USERS);                  // um_sum fused
    finalize_kernel<<<1, 64, 0, stream>>>(aW1, ab1, hdr);
    encode_gemm_kernel<768, 1><<<(N_ITEMS + 63) / 64, 256, 0, stream>>>(
        mf0, W0, b0, g0, be0, m0b, nullptr, N_ITEMS);
    encode_gemm_kernel<384, 1><<<(N_ITEMS + 63) / 64, 256, 0, stream>>>(
        mf1, W1, b1, g1, be1, m1b, nullptr, N_ITEMS);
    copy_kernel<<<1024, 256, 0, stream>>>(user_emb, e0, N_USERS * EMB / 4);
    item_fuse_gemm_kernel<<<(N_ITEMS + 63) / 64, 256, 0, stream>>>(
        item_emb, m0b, m1b, hdr, aW1, aW2, ab2, e0);

    // two propagation layers, no atomics
    spmm_csr_kernel<0><<<(N_NODES + 3) / 4, 256, 0, stream>>>(offs, edges, e0, e0, e1, e1);
    spmm_csr_kernel<1><<<(N_NODES + 3) / 4, 256, 0, stream>>>(offs, edges, e1, e0, e1, out);
}